// Round 8
// baseline (89633.411 us; speedup 1.0000x reference)
//
#include <hip/hip_runtime.h>
#include <math.h>

// B=128, T=256, H=E=1024, L=2, EOS=1
#define NB 128
#define NT 256
#define NH 1024
#define NE 1024
#define G4 4096
#define EOSL 1

// ---------------- workspace layout (float units) — identical to round 7 ------
#define C_OFF    ((size_t)0)          // c [(l*2+dir)][mb 128][b 128][nl 8] = 524,288
#define HT_OFF   ((size_t)524288)     // Ht [2dir][1024n][128b] = 262,144
#define FCZ_OFF  ((size_t)786432)     // fcz [16kp][128b][1024e] = 2,097,152
#define BIAS_OFF ((size_t)2883584)    // 16,384
#define BAR_OFF  ((size_t)2899968)    // 640 ints: [0]=epoch, [16..48)=flags, [64..320)=slots
#define XPH_OFF  ((size_t)2900608)    // 2 parity x 524,288 f
#define XPX_OFF  ((size_t)3949184)    // 131,072 f
#define WP_OFF   ((size_t)4080256)    // 33,554,432 f
#define TOTAL_MIN_F  ((size_t)4080256)
#define TOTAL_PACK_F ((size_t)37634688)   // ~150.5 MB (same as round 7)

typedef __attribute__((ext_vector_type(8))) short s8v;   // 8 bf16 for MFMA A/B
typedef __attribute__((ext_vector_type(4))) float f4v;   // MFMA C/D + asm stores
typedef __attribute__((ext_vector_type(2))) float f2v;
typedef __attribute__((ext_vector_type(2))) unsigned u2v;
typedef __attribute__((ext_vector_type(4))) int   i4v;

__device__ __forceinline__ float sigmoid_stable(float x) {
  if (x >= 0.f) return 1.f / (1.f + expf(-x));
  float ex = expf(x);
  return ex / (1.f + ex);
}
__device__ __forceinline__ unsigned short bf_rne(float x) {
  unsigned u = __float_as_uint(x);
  return (unsigned short)((u + 0x7FFFu + ((u >> 16) & 1u)) >> 16);
}
__device__ __forceinline__ void split_bf(float x, unsigned short& h, unsigned short& l) {
  unsigned u = __float_as_uint(x);
  unsigned hb = (u + 0x7FFFu + ((u >> 16) & 1u)) >> 16;
  h = (unsigned short)hb;
  float r = x - __uint_as_float(hb << 16);   // exact
  l = bf_rne(r);
}
__device__ __forceinline__ void cvt8(float4 a0, float4 a1, s8v& hi, s8v& lo)
{
  const float v[8] = {a0.x, a0.y, a0.z, a0.w, a1.x, a1.y, a1.z, a1.w};
  #pragma unroll
  for (int j = 0; j < 8; j++) {
    unsigned short h, l; split_bf(v[j], h, l);
    hi[j] = (short)h; lo[j] = (short)l;
  }
}

// ---- coherent write-through stores/loads (to/from L3 coherence point).
// k_all never creates dirty L2 lines, so buffer_inv never drops data.
__device__ __forceinline__ void st_f(float* p, float v) {
  asm volatile("global_store_dword %0, %1, off sc0 sc1" :: "v"(p), "v"(v) : "memory");
}
__device__ __forceinline__ void st_u32(unsigned* p, unsigned v) {
  asm volatile("global_store_dword %0, %1, off sc0 sc1" :: "v"(p), "v"(v) : "memory");
}
__device__ __forceinline__ void st_f2(float* p, float a, float b) {
  f2v v; v.x = a; v.y = b;
  asm volatile("global_store_dwordx2 %0, %1, off sc0 sc1" :: "v"(p), "v"(v) : "memory");
}
__device__ __forceinline__ void st_u2(unsigned* p, unsigned a, unsigned b) {
  u2v v; v.x = a; v.y = b;
  asm volatile("global_store_dwordx2 %0, %1, off sc0 sc1" :: "v"(p), "v"(v) : "memory");
}
__device__ __forceinline__ void st_f4(float* p, f4v v) {
  asm volatile("global_store_dwordx4 %0, %1, off sc0 sc1" :: "v"(p), "v"(v) : "memory");
}
__device__ __forceinline__ i4v ld4_coh(const int* p) {
  i4v v;
  asm volatile("global_load_dwordx4 %0, %1, off sc0 sc1\n\ts_waitcnt vmcnt(0)"
               : "=v"(v) : "v"(p) : "memory");
  return v;
}
__device__ __forceinline__ int ld_coh(const int* p) {
  int v;
  asm volatile("global_load_dword %0, %1, off sc0 sc1\n\ts_waitcnt vmcnt(0)"
               : "=v"(v) : "v"(p) : "memory");
  return v;
}

// ---------------- tree grid barrier: slots -> group flags -> epoch -----------
// Contention design: slot line = 16 writers + 1 reader; flag lines = 32 writers
// + 32 single-lane reads; epoch line = 1 writer + 255 slow pollers (s_sleep).
__device__ __forceinline__ void gbar(int* bar, int target, bool inv)
{
  asm volatile("s_waitcnt vmcnt(0)" ::: "memory");   // drain this wave's stores
  __syncthreads();                                   // all waves drained
  const int bid = blockIdx.x, tid = threadIdx.x;
  const int g = bid >> 3, m = bid & 7;
  if (tid == 0) {
    st_u32((unsigned*)(bar + 64 + g * 8 + m), (unsigned)target);
    if (m == 0) {                                    // group leader: my 8 slots
      const int* sp = bar + 64 + g * 8;
      int guard = 0;
      for (;;) {
        i4v a = ld4_coh(sp), b = ld4_coh(sp + 4);
        if (a.x >= target && a.y >= target && a.z >= target && a.w >= target &&
            b.x >= target && b.y >= target && b.z >= target && b.w >= target) break;
        __builtin_amdgcn_s_sleep(2);
        if (++guard > (1 << 17)) break;              // degrade, never hang
      }
      st_u32((unsigned*)(bar + 16 + g), (unsigned)target);
    }
  }
  if (bid == 0 && tid >= 32 && tid < 64) {           // master: all 32 flags
    int guard = 0;
    while (ld_coh(bar + 16 + (tid - 32)) < target) {
      __builtin_amdgcn_s_sleep(2);
      if (++guard > (1 << 17)) break;
    }
  }
  if (bid == 0 && tid == 0)                          // broadcast epoch
    st_u32((unsigned*)bar, (unsigned)target);
  if (bid != 0 && tid == 0) {                        // everyone else: poll epoch
    int guard = 0;
    while (ld_coh(bar) < target) {
      __builtin_amdgcn_s_sleep(4);
      if (++guard > (1 << 17)) break;
    }
  }
  __syncthreads();
  if (inv)
    asm volatile("buffer_inv sc1" ::: "memory");     // drop stale clean lines
}

// frag layouts (verified rounds 0-7):
//  B (acts): lane l holds B[k=(l>>4)*8+r][b=l&15]; frag = 512 hi + 512 lo shorts
//  A (wgts): lane l holds A[slot=l&15][k=(l>>4)*8+r]
//  gate-interleaved mtiles: mtile=mb*2+half; slot s -> m = gate*1024+mb*8+(s&7),
//  gate = half*2+(s>>3).  C/D: col=lane&15 (b), row slot=(lane>>4)*4+reg.

// ---------------- init ----------------
__global__ void k_init(const int* yy, const float* h_t, const float* h_tr,
                       const float* c0, const float* c0r,
                       const float* b_ih, const float* b_hh,
                       const float* b_ihr, const float* b_hhr,
                       const float* emb,
                       unsigned short* xph, unsigned short* xpx,
                       float* call, float* bias, int* bar)
{
  int idx = blockIdx.x * 256 + threadIdx.x;   // 2048 blocks -> 524288
  if (idx < 2 * 2048 * 128) {                 // XPH parity-0
    int dir = idx / (2048 * 128); int rem = idx % (2048 * 128);
    int row = rem >> 7, b = rem & 127;
    int l = row >> 10, n = row & 1023;
    const float* src = dir ? h_tr : h_t;
    float v = src[((size_t)l * 128 + b) * 1024 + n];
    unsigned short h, lo; split_bf(v, h, lo);
    size_t off = ((size_t)(dir * 64 + (row >> 5)) * 8 + (b >> 4)) * 1024
               + ((b & 15) + 16 * ((n >> 3) & 3)) * 8 + (n & 7);
    xph[off] = h; xph[off + 512] = lo;
  }
  if (idx < 4 * 1024 * 128) {                 // c [(ld)][mb][b][nl]
    int ld = idx / (1024 * 128); int l = ld >> 1;
    int rem = idx % (1024 * 128);
    int mb = rem >> 10, nl = rem & 7;
    const float* cs = (ld & 1) ? c0r : c0;
    call[idx] = cs[l * 1024 + mb * 8 + nl];
  }
  if (idx < 4 * 4096) {                       // bias[(l*2+dir)][m]
    int ld = idx / 4096; int l = ld >> 1, dir = ld & 1;
    int m = idx & 4095;
    bias[idx] = (dir ? b_ihr : b_ih)[l * 4096 + m] + (dir ? b_hhr : b_hh)[l * 4096 + m];
  }
  if (idx < 128 * 1024) {                     // XPX: x0 = emb[yy[:,0]]
    int b = idx >> 10, k = idx & 1023;
    int e = yy[b * NT];
    float v = emb[(size_t)e * 1024 + k];
    unsigned short h, lo; split_bf(v, h, lo);
    size_t off = ((size_t)(k >> 5) * 8 + (b >> 4)) * 1024
               + ((b & 15) + 16 * ((k >> 3) & 3)) * 8 + (k & 7);
    xpx[off] = h; xpx[off + 512] = lo;
  }
  if (idx < 640) bar[idx] = 0;
}

// ---------------- one-time weight pre-split (gate-interleaved mtiles) --------
__global__ void k_packW(const float* W_ih, const float* W_hh,
                        const float* W_ihr, const float* W_hhr,
                        unsigned short* WP)
{
  int idx = blockIdx.x * 256 + threadIdx.x;   // 16384 blocks -> 4,194,304
  int l = idx & 63;
  int frag = idx >> 6;
  int ktile = frag & 63;
  int mtile = (frag >> 6) & 255;
  int ld = frag >> 14;
  int layer = ld >> 1, dir = ld & 1;
  int s = l & 15;
  int mbb = mtile >> 1, half = mtile & 1;
  int gate = half * 2 + (s >> 3);
  int m = gate * 1024 + mbb * 8 + (s & 7);
  int kg = ktile * 32 + (l >> 4) * 8;
  const float* base;
  if (kg < 1024) base = (dir ? W_ihr : W_ih) + ((size_t)layer * 4096 + m) * 1024 + kg;
  else           base = (dir ? W_hhr : W_hh) + ((size_t)layer * 4096 + m) * 1024 + (kg - 1024);
  float4 a0 = *(const float4*)base, a1 = *(const float4*)(base + 4);
  s8v hi, lo; cvt8(a0, a1, hi, lo);
  unsigned short* outp = WP + (size_t)frag * 1024 + l * 8;
  *(s8v*)outp = hi;
  *(s8v*)(outp + 512) = lo;
}

// ---------------- reduction-tree helpers (verified round 3) ------------------
__device__ __forceinline__ void red_write(float* red, int slot, int l, const f4v (&acc)[2][8])
{
  #pragma unroll
  for (int mt = 0; mt < 2; mt++)
    #pragma unroll
    for (int bt = 0; bt < 8; bt++)
      *(f4v*)&red[(size_t)slot * 4096 + (mt * 8 + bt) * 256 + l * 4] = acc[mt][bt];
}
__device__ __forceinline__ void red_add(const float* red, int slot, int l, f4v (&acc)[2][8])
{
  #pragma unroll
  for (int mt = 0; mt < 2; mt++)
    #pragma unroll
    for (int bt = 0; bt < 8; bt++)
      acc[mt][bt] += *(const f4v*)&red[(size_t)slot * 4096 + (mt * 8 + bt) * 256 + l * 4];
}

// prefetch units for the packed gemm
__device__ __forceinline__ void gloadW(const unsigned short* Wb, int kk,
                                       s8v (&h)[2], s8v (&lo)[2])
{
  #pragma unroll
  for (int mt = 0; mt < 2; mt++) {
    const unsigned short* q = Wb + ((size_t)(mt * 64 + kk) << 10);
    h[mt] = *(const s8v*)q; lo[mt] = *(const s8v*)(q + 512);
  }
}
__device__ __forceinline__ void gloadB(const unsigned short* Bb, int kk,
                                       s8v (&h)[8], s8v (&lo)[8])
{
  #pragma unroll
  for (int bt = 0; bt < 8; bt++) {
    const unsigned short* q = Bb + ((size_t)(kk * 8 + bt) << 10);
    h[bt] = *(const s8v*)q; lo[bt] = *(const s8v*)(q + 512);
  }
}

struct KP {
  const unsigned short* WP;
  const float* Wih; const float* Whh; const float* Wihr; const float* Whhr;
  const float* bias; float* c; float* Ht; float* fcz;
  unsigned short* xph; unsigned short* xpx;
  const float* fcW; const float* fcb; const float* emb;
  float* out; int* bar;
};

// ---------------- persistent kernel: all 256 steps, 4 grid barriers/step -----
template<int PACKED>
__global__ __launch_bounds__(512, 1) void k_all(KP p)
{
  __shared__ __align__(16) float lds[16384];           // 64 KB, reused per phase
  const int bid = blockIdx.x, tid = threadIdx.x;
  const int l = tid & 63, w = tid >> 6;                // w = K-chunk 0..7 (gemm)
  const int dir = bid >> 7, mb = bid & 127;
  const int lr = l & 15, lk = l >> 4;
  int nbar = 0;
  int ended_reg = 0;                                   // block b owns batch b

  for (int t = 0; t < NT; t++) {
    unsigned short* xpR = p.xph + (size_t)(t & 1) * 1048576;        // read h
    unsigned short* xpW = p.xph + (size_t)((t & 1) ^ 1) * 1048576;  // write h

    for (int layer = 0; layer < 2; layer++) {
      // ---- per-wave B fragment base ----
      const unsigned short* Bb;
      if (layer == 0)
        Bb = (w < 4) ? p.xpx + (size_t)w * 65536
                     : xpR + (size_t)(dir * 64 + (w - 4) * 8) * 8192;
      else
        Bb = (w < 4) ? xpW + (size_t)(dir * 64 + w * 8) * 8192
                     : xpR + (size_t)(dir * 64 + 32 + (w - 4) * 8) * 8192;
      Bb += l * 8;

      f4v acc[2][8];
      #pragma unroll
      for (int mt = 0; mt < 2; mt++)
        #pragma unroll
        for (int bt = 0; bt < 8; bt++)
          acc[mt][bt] = (f4v)(0.0f);

      if (PACKED) {
        const unsigned short* Wb = p.WP + (size_t)(layer * 2 + dir) * 16777216ULL
            + (((size_t)(mb * 2) * 64 + (size_t)w * 8) << 10) + l * 8;
        s8v whc[2], wlc[2], whn[2], wln[2];
        s8v bhc[8], blc[8], bhn[8], bln[8];
        gloadW(Wb, 0, whc, wlc);
        gloadB(Bb, 0, bhc, blc);
        #pragma unroll 1
        for (int kk = 0; kk < 8; kk++) {
          if (kk < 7) {                        // depth-1 prefetch of W AND B
            gloadW(Wb, kk + 1, whn, wln);
            gloadB(Bb, kk + 1, bhn, bln);
          }
          #pragma unroll
          for (int mt = 0; mt < 2; mt++)
            #pragma unroll
            for (int bt = 0; bt < 8; bt++) {
              acc[mt][bt] = __builtin_amdgcn_mfma_f32_16x16x32_bf16(whc[mt], bhc[bt], acc[mt][bt], 0, 0, 0);
              acc[mt][bt] = __builtin_amdgcn_mfma_f32_16x16x32_bf16(whc[mt], blc[bt], acc[mt][bt], 0, 0, 0);
              acc[mt][bt] = __builtin_amdgcn_mfma_f32_16x16x32_bf16(wlc[mt], bhc[bt], acc[mt][bt], 0, 0, 0);
            }
          if (kk < 7) {
            whc[0] = whn[0]; whc[1] = whn[1];
            wlc[0] = wln[0]; wlc[1] = wln[1];
            #pragma unroll
            for (int bt = 0; bt < 8; bt++) { bhc[bt] = bhn[bt]; blc[bt] = bln[bt]; }
          }
        }
      } else {
        const float* Wsel = ((w < 4) ? (dir ? p.Wihr : p.Wih) : (dir ? p.Whhr : p.Whh))
                          + (size_t)layer * 4194304;
        int col0 = (w & 3) * 256 + lk * 8;
        const float* Wrow[2];
        Wrow[0] = Wsel + ((size_t)(((lr >> 3)) * 1024 + mb * 8 + (lr & 7))) * 1024 + col0;
        Wrow[1] = Wsel + ((size_t)((2 + (lr >> 3)) * 1024 + mb * 8 + (lr & 7))) * 1024 + col0;
        float4 ac[2][2];
        #pragma unroll
        for (int mt = 0; mt < 2; mt++) {
          ac[mt][0] = *(const float4*)(Wrow[mt]);
          ac[mt][1] = *(const float4*)(Wrow[mt] + 4);
        }
        #pragma unroll 1
        for (int kk = 0; kk < 8; kk++) {
          s8v bh[8], bl[8];
          gloadB(Bb, kk, bh, bl);
          float4 an[2][2];
          if (kk < 7) {
            #pragma unroll
            for (int mt = 0; mt < 2; mt++) {
              an[mt][0] = *(const float4*)(Wrow[mt] + (kk + 1) * 32);
              an[mt][1] = *(const float4*)(Wrow[mt] + (kk + 1) * 32 + 4);
            }
          }
          #pragma unroll
          for (int mt = 0; mt < 2; mt++) {
            s8v wh, wl;
            cvt8(ac[mt][0], ac[mt][1], wh, wl);
            #pragma unroll
            for (int bt = 0; bt < 8; bt++) {
              acc[mt][bt] = __builtin_amdgcn_mfma_f32_16x16x32_bf16(wh, bh[bt], acc[mt][bt], 0, 0, 0);
              acc[mt][bt] = __builtin_amdgcn_mfma_f32_16x16x32_bf16(wh, bl[bt], acc[mt][bt], 0, 0, 0);
              acc[mt][bt] = __builtin_amdgcn_mfma_f32_16x16x32_bf16(wl, bh[bt], acc[mt][bt], 0, 0, 0);
            }
          }
          if (kk < 7) {
            #pragma unroll
            for (int mt = 0; mt < 2; mt++) { ac[mt][0] = an[mt][0]; ac[mt][1] = an[mt][1]; }
          }
        }
      }

      // ---- in-block K reduction: 8 -> 4 -> 2 -> zs stage ----
      if (w >= 4) red_write(lds, w - 4, l, acc);
      __syncthreads();
      if (w < 4) red_add(lds, w, l, acc);
      __syncthreads();
      if (w == 2 || w == 3) red_write(lds, w - 2, l, acc);
      __syncthreads();
      if (w < 2) red_add(lds, w, l, acc);
      __syncthreads();
      if (w < 2) red_write(lds, w, l, acc);
      __syncthreads();
      float* zs = lds + 8192;                 // [2mt][16slot][128b]
      #pragma unroll
      for (int vi = 0; vi < 2; vi++) {
        int v = tid + vi * 512;
        f4v s = *(const f4v*)&lds[(size_t)v * 4];
        s += *(const f4v*)&lds[4096 + (size_t)v * 4];
        int frag = v >> 6, lane = v & 63;
        int mt = frag >> 3, bt = frag & 7;
        int s0 = (lane >> 4) * 4, bcol = bt * 16 + (lane & 15);
        #pragma unroll
        for (int r = 0; r < 4; r++)
          zs[mt * 2048 + (s0 + r) * 128 + bcol] = s[r];
      }
      __syncthreads();

      // ---- fused gates: thread = (b, 4 consecutive n); coalesced stores ----
      int ldg = layer * 2 + dir;
      if (tid < 256) {
        int b = tid & 127, q = tid >> 7;
        float* cp = p.c + ((((size_t)ldg * 128 + mb) * 128 + b) * 8 + q * 4);
        f4v cold = *(const f4v*)cp;
        f4v cnew;
        float hs[4];
        #pragma unroll
        for (int j = 0; j < 4; j++) {
          int nl = q * 4 + j;
          int n = mb * 8 + nl;
          float iv = zs[nl * 128 + b]              + p.bias[ldg * 4096 + n];
          float fv = zs[(nl + 8) * 128 + b]        + p.bias[ldg * 4096 + 1024 + n];
          float gv = zs[2048 + nl * 128 + b]       + p.bias[ldg * 4096 + 2048 + n];
          float ov = zs[2048 + (nl + 8) * 128 + b] + p.bias[ldg * 4096 + 3072 + n];
          float co = cold[j];
          float cn = sigmoid_stable(fv) * co + sigmoid_stable(iv) * tanhf(gv);
          float hn = sigmoid_stable(ov) * tanhf(cn);
          cnew[j] = cn;
          hs[j] = hn;
        }
        st_f4(cp, cnew);
        unsigned short hh[4], ll[4];
        #pragma unroll
        for (int j = 0; j < 4; j++) split_bf(hs[j], hh[j], ll[j]);
        int kt = layer * 32 + (mb >> 2);
        size_t off = ((size_t)(dir * 64 + kt) * 8 + (b >> 4)) * 1024
                   + ((size_t)((b & 15) + 16 * (mb & 3))) * 8 + q * 4;
        st_u2((unsigned*)(xpW + off),
              (unsigned)hh[0] | ((unsigned)hh[1] << 16),
              (unsigned)hh[2] | ((unsigned)hh[3] << 16));
        st_u2((unsigned*)(xpW + off + 512),
              (unsigned)ll[0] | ((unsigned)ll[1] << 16),
              (unsigned)ll[2] | ((unsigned)ll[3] << 16));
        if (layer == 1) {
          #pragma unroll
          for (int j = 0; j < 4; j++) {
            int n = mb * 8 + q * 4 + j;
            st_f(p.Ht + (size_t)dir * 131072 + (size_t)n * 128 + b, hs[j]);
          }
        }
      }
      ++nbar; gbar(p.bar, nbar, true);
    } // layer

    // ---- fc: fcz[kp][b][e] partials, 256 blocks = (16 et, 16 kp) ----
    {
      int et = bid & 15, kp = bid >> 4;
      int e0 = et * 64, k00 = kp * 128;
      float* in_s = lds;            // [128][36]
      float* w_s  = lds + 4608;     // [64][36]
      int e_sub = tid & 7, bg = tid >> 3, b0 = bg * 2;
      float accf[8][2];
      #pragma unroll
      for (int je = 0; je < 8; je++) { accf[je][0] = 0.f; accf[je][1] = 0.f; }
      for (int kc = 0; kc < 128; kc += 32) {
        #pragma unroll
        for (int i = 0; i < 2; i++) {
          int flat = tid + 512 * i, r = flat >> 3, f4i = flat & 7;
          float4 v = *(const float4*)(p.Ht + (size_t)r * 2048 + k00 + kc + f4i * 4);
          int sw = (f4i ^ (r >> 2)) & 7;
          *(float4*)&in_s[r * 36 + sw * 4] = v;
        }
        {
          int r = tid >> 3, f4i = tid & 7;
          *(float4*)&w_s[r * 36 + f4i * 4] =
              *(const float4*)(p.fcW + (size_t)(e0 + r) * 2048 + k00 + kc + f4i * 4);
        }
        __syncthreads();
        #pragma unroll
        for (int kq = 0; kq < 8; kq++) {
          int ksw = (kq ^ (bg >> 1)) & 7;
          float4 a0 = *(const float4*)&in_s[b0 * 36 + ksw * 4];
          float4 a1 = *(const float4*)&in_s[(b0 + 1) * 36 + ksw * 4];
          #pragma unroll
          for (int je = 0; je < 8; je++) {
            float4 w4 = *(const float4*)&w_s[(e_sub + 8 * je) * 36 + kq * 4];
            accf[je][0] += a0.x * w4.x + a0.y * w4.y + a0.z * w4.z + a0.w * w4.w;
            accf[je][1] += a1.x * w4.x + a1.y * w4.y + a1.z * w4.z + a1.w * w4.w;
          }
        }
        __syncthreads();
      }
      // stage to LDS transpose, then 64B-contiguous coherent stores
      #pragma unroll
      for (int je = 0; je < 8; je++) {
        lds[(b0    ) * 68 + e_sub + 8 * je] = accf[je][0];
        lds[(b0 + 1) * 68 + e_sub + 8 * je] = accf[je][1];
      }
      __syncthreads();
      {
        int row = tid >> 2, ch = tid & 3;
        float* gp = p.fcz + ((size_t)kp * 128 + row) * 1024 + e0 + ch * 16;
        #pragma unroll
        for (int i = 0; i < 4; i++)
          st_f4(gp + 4 * i, *(const f4v*)&lds[row * 68 + ch * 16 + 4 * i]);
      }
      ++nbar; gbar(p.bar, nbar, true);
    }

    // ---- final: logits, argmax, softmax, pack next x (blocks 0..127) ----
    if (bid < 128) {
      int b = bid;
      float* sval = lds;
      int*   sidx = (int*)(lds + 512);
      float* ssum = lds + 1024;
      bool end = (ended_reg != 0);
      int e2 = tid * 2;
      float vx = p.fcb[e2], vy = p.fcb[e2 + 1];
      #pragma unroll
      for (int q = 0; q < 16; q++) {
        const float* f = &p.fcz[((size_t)q * 128 + b) * 1024 + e2];
        vx += f[0]; vy += f[1];
      }
      if (end) { vx = (e2 == EOSL) ? 1.f : 0.f; vy = (e2 + 1 == EOSL) ? 1.f : 0.f; }
      float bv; int bi;
      if (vy > vx) { bv = vy; bi = e2 + 1; } else { bv = vx; bi = e2; }
      sval[tid] = bv; sidx[tid] = bi;
      __syncthreads();
      for (int s = 256; s > 0; s >>= 1) {
        if (tid < s) {
          float ov = sval[tid + s]; int oi = sidx[tid + s];
          if (ov > sval[tid] || (ov == sval[tid] && oi < sidx[tid])) { sval[tid] = ov; sidx[tid] = oi; }
        }
        __syncthreads();
      }
      float m = sval[0]; int label = sidx[0];
      {
        int k0 = tid * 2;
        float ex = p.emb[(size_t)label * 1024 + k0];
        float ey = p.emb[(size_t)label * 1024 + k0 + 1];
        size_t off = ((size_t)(k0 >> 5) * 8 + (b >> 4)) * 1024
                   + ((b & 15) + 16 * ((k0 >> 3) & 3)) * 8 + (k0 & 7);
        unsigned short h0, l0, h1, l1;
        split_bf(ex, h0, l0); split_bf(ey, h1, l1);
        st_u32((unsigned*)(p.xpx + off),       (unsigned)h0 | ((unsigned)h1 << 16));
        st_u32((unsigned*)(p.xpx + off + 512), (unsigned)l0 | ((unsigned)l1 << 16));
      }
      float ex0 = expf(vx - m), ex1 = expf(vy - m);
      ssum[tid] = ex0 + ex1;
      __syncthreads();
      for (int s = 256; s > 0; s >>= 1) { if (tid < s) ssum[tid] += ssum[tid + s]; __syncthreads(); }
      float inv = 1.f / ssum[0];
      float* orow = p.out + ((size_t)b * NT + t) * NE + e2;
      st_f2(orow, ex0 * inv, ex1 * inv);
      ended_reg = (end || label == EOSL) ? 1 : 0;
    }
    ++nbar; gbar(p.bar, nbar, true);
  } // t
}

extern "C" void kernel_launch(void* const* d_in, const int* in_sizes, int n_in,
                              void* d_out, int out_size, void* d_ws, size_t ws_size,
                              hipStream_t stream)
{
  const int*   yy    = (const int*)d_in[0];
  const float* h_t   = (const float*)d_in[1];
  const float* h_tr  = (const float*)d_in[2];
  const float* emb   = (const float*)d_in[4];
  const float* W_ih  = (const float*)d_in[5];
  const float* W_hh  = (const float*)d_in[6];
  const float* b_ih  = (const float*)d_in[7];
  const float* b_hh  = (const float*)d_in[8];
  const float* W_ihr = (const float*)d_in[9];
  const float* W_hhr = (const float*)d_in[10];
  const float* b_ihr = (const float*)d_in[11];
  const float* b_hhr = (const float*)d_in[12];
  const float* c0    = (const float*)d_in[13];
  const float* c0r   = (const float*)d_in[14];
  const float* fc_W  = (const float*)d_in[15];
  const float* fc_b  = (const float*)d_in[16];
  float* out = (float*)d_out;

  float* ws = (float*)d_ws;
  KP p;
  p.c     = ws + C_OFF;
  p.Ht    = ws + HT_OFF;
  p.fcz   = ws + FCZ_OFF;
  p.bias  = ws + BIAS_OFF;
  p.bar   = (int*)(ws + BAR_OFF);
  p.xph   = (unsigned short*)(ws + XPH_OFF);
  p.xpx   = (unsigned short*)(ws + XPX_OFF);
  p.WP    = (const unsigned short*)(ws + WP_OFF);
  p.Wih = W_ih; p.Whh = W_hh; p.Wihr = W_ihr; p.Whhr = W_hhr;
  p.fcW = fc_W; p.fcb = fc_b; p.emb = emb;
  p.out = out;
  bool packed = ws_size >= TOTAL_PACK_F * sizeof(float);

  k_init<<<2048, 256, 0, stream>>>(yy, h_t, h_tr, c0, c0r, b_ih, b_hh, b_ihr, b_hhr,
                                   emb, p.xph, p.xpx, p.c, (float*)p.bias, p.bar);
  if (packed)
    k_packW<<<16384, 256, 0, stream>>>(W_ih, W_hh, W_ihr, W_hhr,
                                       (unsigned short*)p.WP);

  if (packed) k_all<1><<<256, 512, 0, stream>>>(p);
  else        k_all<0><<<256, 512, 0, stream>>>(p);
}

// Round 9
// 46751.245 us; speedup vs baseline: 1.9172x; 1.9172x over previous
//
#include <hip/hip_runtime.h>
#include <math.h>

// B=128, T=256, H=E=1024, L=2, EOS=1
#define NB 128
#define NT 256
#define NH 1024
#define NE 1024
#define G4 4096
#define EOSL 1

// ---------------- workspace layout (float units) — identical to round 7 ------
#define C_OFF    ((size_t)0)          // c [(l*2+dir)][mb 128][b 128][nl 8] = 524,288
#define HT_OFF   ((size_t)524288)     // Ht [2dir][1024n][128b] = 262,144
#define FCZ_OFF  ((size_t)786432)     // fcz [16kp][128b][1024e] = 2,097,152
#define BIAS_OFF ((size_t)2883584)    // 16,384
#define BAR_OFF  ((size_t)2899968)    // 640 ints: [0]=epoch, [16..48)=flags, [64..320)=slots
#define XPH_OFF  ((size_t)2900608)    // 2 parity x 524,288 f
#define XPX_OFF  ((size_t)3949184)    // 131,072 f
#define WP_OFF   ((size_t)4080256)    // 33,554,432 f
#define TOTAL_MIN_F  ((size_t)4080256)
#define TOTAL_PACK_F ((size_t)37634688)   // ~150.5 MB

typedef __attribute__((ext_vector_type(8))) short s8v;   // 8 bf16 for MFMA A/B
typedef __attribute__((ext_vector_type(4))) float f4v;   // MFMA C/D + asm stores
typedef __attribute__((ext_vector_type(2))) float f2v;
typedef __attribute__((ext_vector_type(2))) unsigned u2v;
typedef __attribute__((ext_vector_type(4))) int   i4v;

__device__ __forceinline__ float sigmoid_stable(float x) {
  if (x >= 0.f) return 1.f / (1.f + expf(-x));
  float ex = expf(x);
  return ex / (1.f + ex);
}
__device__ __forceinline__ unsigned short bf_rne(float x) {
  unsigned u = __float_as_uint(x);
  return (unsigned short)((u + 0x7FFFu + ((u >> 16) & 1u)) >> 16);
}
__device__ __forceinline__ void split_bf(float x, unsigned short& h, unsigned short& l) {
  unsigned u = __float_as_uint(x);
  unsigned hb = (u + 0x7FFFu + ((u >> 16) & 1u)) >> 16;
  h = (unsigned short)hb;
  float r = x - __uint_as_float(hb << 16);   // exact
  l = bf_rne(r);
}
__device__ __forceinline__ void cvt8(float4 a0, float4 a1, s8v& hi, s8v& lo)
{
  const float v[8] = {a0.x, a0.y, a0.z, a0.w, a1.x, a1.y, a1.z, a1.w};
  #pragma unroll
  for (int j = 0; j < 8; j++) {
    unsigned short h, l; split_bf(v[j], h, l);
    hi[j] = (short)h; lo[j] = (short)l;
  }
}

// ---- coherent write-through stores/loads (to/from L3 coherence point).
// k_all never creates dirty L2 lines, so buffer_inv never drops data.
__device__ __forceinline__ void st_f(float* p, float v) {
  asm volatile("global_store_dword %0, %1, off sc0 sc1" :: "v"(p), "v"(v) : "memory");
}
__device__ __forceinline__ void st_u32(unsigned* p, unsigned v) {
  asm volatile("global_store_dword %0, %1, off sc0 sc1" :: "v"(p), "v"(v) : "memory");
}
__device__ __forceinline__ void st_f2(float* p, float a, float b) {
  f2v v; v.x = a; v.y = b;
  asm volatile("global_store_dwordx2 %0, %1, off sc0 sc1" :: "v"(p), "v"(v) : "memory");
}
__device__ __forceinline__ void st_u2(unsigned* p, unsigned a, unsigned b) {
  u2v v; v.x = a; v.y = b;
  asm volatile("global_store_dwordx2 %0, %1, off sc0 sc1" :: "v"(p), "v"(v) : "memory");
}
__device__ __forceinline__ void st_f4(float* p, f4v v) {
  asm volatile("global_store_dwordx4 %0, %1, off sc0 sc1" :: "v"(p), "v"(v) : "memory");
}
__device__ __forceinline__ i4v ld4_coh(const int* p) {
  i4v v;
  asm volatile("global_load_dwordx4 %0, %1, off sc0 sc1\n\ts_waitcnt vmcnt(0)"
               : "=v"(v) : "v"(p) : "memory");
  return v;
}
__device__ __forceinline__ int ld_coh(const int* p) {
  int v;
  asm volatile("global_load_dword %0, %1, off sc0 sc1\n\ts_waitcnt vmcnt(0)"
               : "=v"(v) : "v"(p) : "memory");
  return v;
}

// ---------------- tree grid barrier: slots -> group flags -> epoch -----------
// Contention design: slot line = 16 writers + 1 reader; flag lines = 32 writers
// + 32 single-lane reads; epoch line = 1 writer + 255 slow pollers (s_sleep).
__device__ __forceinline__ void gbar(int* bar, int target, bool inv)
{
  asm volatile("s_waitcnt vmcnt(0)" ::: "memory");   // drain this wave's stores
  __syncthreads();                                   // all waves drained
  const int bid = blockIdx.x, tid = threadIdx.x;
  const int g = bid >> 3, m = bid & 7;
  if (tid == 0) {
    st_u32((unsigned*)(bar + 64 + g * 8 + m), (unsigned)target);
    if (m == 0) {                                    // group leader: my 8 slots
      const int* sp = bar + 64 + g * 8;
      int guard = 0;
      for (;;) {
        i4v a = ld4_coh(sp), b = ld4_coh(sp + 4);
        if (a.x >= target && a.y >= target && a.z >= target && a.w >= target &&
            b.x >= target && b.y >= target && b.z >= target && b.w >= target) break;
        __builtin_amdgcn_s_sleep(2);
        if (++guard > (1 << 17)) break;              // degrade, never hang
      }
      st_u32((unsigned*)(bar + 16 + g), (unsigned)target);
    }
  }
  if (bid == 0 && tid >= 32 && tid < 64) {           // master: all 32 flags
    int guard = 0;
    while (ld_coh(bar + 16 + (tid - 32)) < target) {
      __builtin_amdgcn_s_sleep(2);
      if (++guard > (1 << 17)) break;
    }
  }
  if (bid == 0 && tid == 0)                          // broadcast epoch
    st_u32((unsigned*)bar, (unsigned)target);
  if (bid != 0 && tid == 0) {                        // everyone else: poll epoch
    int guard = 0;
    while (ld_coh(bar) < target) {
      __builtin_amdgcn_s_sleep(4);
      if (++guard > (1 << 17)) break;
    }
  }
  __syncthreads();
  if (inv)
    asm volatile("buffer_inv sc1" ::: "memory");     // drop stale clean lines
}

// frag layouts (verified rounds 0-7):
//  B (acts): lane l holds B[k=(l>>4)*8+r][b=l&15]; frag = 512 hi + 512 lo shorts
//  A (wgts): lane l holds A[slot=l&15][k=(l>>4)*8+r]
//  gate-interleaved mtiles: mtile=mb*2+half; slot s -> m = gate*1024+mb*8+(s&7),
//  gate = half*2+(s>>3).  C/D: col=lane&15 (b), row slot=(lane>>4)*4+reg.

// ---------------- init ----------------
__global__ void k_init(const int* yy, const float* h_t, const float* h_tr,
                       const float* c0, const float* c0r,
                       const float* b_ih, const float* b_hh,
                       const float* b_ihr, const float* b_hhr,
                       const float* emb,
                       unsigned short* xph, unsigned short* xpx,
                       float* call, float* bias, int* bar)
{
  int idx = blockIdx.x * 256 + threadIdx.x;   // 2048 blocks -> 524288
  if (idx < 2 * 2048 * 128) {                 // XPH parity-0
    int dir = idx / (2048 * 128); int rem = idx % (2048 * 128);
    int row = rem >> 7, b = rem & 127;
    int l = row >> 10, n = row & 1023;
    const float* src = dir ? h_tr : h_t;
    float v = src[((size_t)l * 128 + b) * 1024 + n];
    unsigned short h, lo; split_bf(v, h, lo);
    size_t off = ((size_t)(dir * 64 + (row >> 5)) * 8 + (b >> 4)) * 1024
               + ((b & 15) + 16 * ((n >> 3) & 3)) * 8 + (n & 7);
    xph[off] = h; xph[off + 512] = lo;
  }
  if (idx < 4 * 1024 * 128) {                 // c [(ld)][mb][b][nl]
    int ld = idx / (1024 * 128); int l = ld >> 1;
    int rem = idx % (1024 * 128);
    int mb = rem >> 10, nl = rem & 7;
    const float* cs = (ld & 1) ? c0r : c0;
    call[idx] = cs[l * 1024 + mb * 8 + nl];
  }
  if (idx < 4 * 4096) {                       // bias[(l*2+dir)][m]
    int ld = idx / 4096; int l = ld >> 1, dir = ld & 1;
    int m = idx & 4095;
    bias[idx] = (dir ? b_ihr : b_ih)[l * 4096 + m] + (dir ? b_hhr : b_hh)[l * 4096 + m];
  }
  if (idx < 128 * 1024) {                     // XPX: x0 = emb[yy[:,0]]
    int b = idx >> 10, k = idx & 1023;
    int e = yy[b * NT];
    float v = emb[(size_t)e * 1024 + k];
    unsigned short h, lo; split_bf(v, h, lo);
    size_t off = ((size_t)(k >> 5) * 8 + (b >> 4)) * 1024
               + ((b & 15) + 16 * ((k >> 3) & 3)) * 8 + (k & 7);
    xpx[off] = h; xpx[off + 512] = lo;
  }
  if (idx < 640) bar[idx] = 0;
}

// ---------------- one-time weight pre-split (gate-interleaved mtiles) --------
__global__ void k_packW(const float* W_ih, const float* W_hh,
                        const float* W_ihr, const float* W_hhr,
                        unsigned short* WP)
{
  int idx = blockIdx.x * 256 + threadIdx.x;   // 16384 blocks -> 4,194,304
  int l = idx & 63;
  int frag = idx >> 6;
  int ktile = frag & 63;
  int mtile = (frag >> 6) & 255;
  int ld = frag >> 14;
  int layer = ld >> 1, dir = ld & 1;
  int s = l & 15;
  int mbb = mtile >> 1, half = mtile & 1;
  int gate = half * 2 + (s >> 3);
  int m = gate * 1024 + mbb * 8 + (s & 7);
  int kg = ktile * 32 + (l >> 4) * 8;
  const float* base;
  if (kg < 1024) base = (dir ? W_ihr : W_ih) + ((size_t)layer * 4096 + m) * 1024 + kg;
  else           base = (dir ? W_hhr : W_hh) + ((size_t)layer * 4096 + m) * 1024 + (kg - 1024);
  float4 a0 = *(const float4*)base, a1 = *(const float4*)(base + 4);
  s8v hi, lo; cvt8(a0, a1, hi, lo);
  unsigned short* outp = WP + (size_t)frag * 1024 + l * 8;
  *(s8v*)outp = hi;
  *(s8v*)(outp + 512) = lo;
}

// ---------------- reduction-tree helpers (verified round 3) ------------------
__device__ __forceinline__ void red_write(float* red, int slot, int l, const f4v (&acc)[2][8])
{
  #pragma unroll
  for (int mt = 0; mt < 2; mt++)
    #pragma unroll
    for (int bt = 0; bt < 8; bt++)
      *(f4v*)&red[(size_t)slot * 4096 + (mt * 8 + bt) * 256 + l * 4] = acc[mt][bt];
}
__device__ __forceinline__ void red_add(const float* red, int slot, int l, f4v (&acc)[2][8])
{
  #pragma unroll
  for (int mt = 0; mt < 2; mt++)
    #pragma unroll
    for (int bt = 0; bt < 8; bt++)
      acc[mt][bt] += *(const f4v*)&red[(size_t)slot * 4096 + (mt * 8 + bt) * 256 + l * 4];
}

__device__ __forceinline__ void gloadW(const unsigned short* Wb, int kk,
                                       s8v (&h)[2], s8v (&lo)[2])
{
  #pragma unroll
  for (int mt = 0; mt < 2; mt++) {
    const unsigned short* q = Wb + ((size_t)(mt * 64 + kk) << 10);
    h[mt] = *(const s8v*)q; lo[mt] = *(const s8v*)(q + 512);
  }
}
__device__ __forceinline__ void gloadB(const unsigned short* Bb, int kk,
                                       s8v (&h)[8], s8v (&lo)[8])
{
  #pragma unroll
  for (int bt = 0; bt < 8; bt++) {
    const unsigned short* q = Bb + ((size_t)(kk * 8 + bt) << 10);
    h[bt] = *(const s8v*)q; lo[bt] = *(const s8v*)(q + 512);
  }
}

struct KP {
  const unsigned short* WP;
  const float* Wih; const float* Whh; const float* Wihr; const float* Whhr;
  const float* bias; float* c; float* Ht; float* fcz;
  unsigned short* xph; unsigned short* xpx;
  const float* fcW; const float* fcb; const float* emb;
  float* out; int* bar;
};

// ---------------- persistent kernel: all 256 steps, 4 grid barriers/step -----
// NOTE launch_bounds(512,2): pins VGPR<=128. R8's (512,1) + deep B-prefetch
// spilled to scratch (+400 MB/step traffic, 2x slowdown). Keep R7's schedule.
template<int PACKED>
__global__ __launch_bounds__(512, 2) void k_all(KP p)
{
  __shared__ __align__(16) float lds[16384];           // 64 KB, reused per phase
  const int bid = blockIdx.x, tid = threadIdx.x;
  const int l = tid & 63, w = tid >> 6;                // w = K-chunk 0..7 (gemm)
  const int dir = bid >> 7, mb = bid & 127;
  const int lr = l & 15, lk = l >> 4;
  int nbar = 0;
  int ended_reg = 0;                                   // block b owns batch b

  for (int t = 0; t < NT; t++) {
    unsigned short* xpR = p.xph + (size_t)(t & 1) * 1048576;        // read h
    unsigned short* xpW = p.xph + (size_t)((t & 1) ^ 1) * 1048576;  // write h

    for (int layer = 0; layer < 2; layer++) {
      // ---- per-wave B fragment base ----
      const unsigned short* Bb;
      if (layer == 0)
        Bb = (w < 4) ? p.xpx + (size_t)w * 65536
                     : xpR + (size_t)(dir * 64 + (w - 4) * 8) * 8192;
      else
        Bb = (w < 4) ? xpW + (size_t)(dir * 64 + w * 8) * 8192
                     : xpR + (size_t)(dir * 64 + 32 + (w - 4) * 8) * 8192;
      Bb += l * 8;

      f4v acc[2][8];
      #pragma unroll
      for (int mt = 0; mt < 2; mt++)
        #pragma unroll
        for (int bt = 0; bt < 8; bt++)
          acc[mt][bt] = (f4v)(0.0f);

      if (PACKED) {
        const unsigned short* Wb = p.WP + (size_t)(layer * 2 + dir) * 16777216ULL
            + (((size_t)(mb * 2) * 64 + (size_t)w * 8) << 10) + l * 8;
        s8v whc[2], wlc[2];
        gloadW(Wb, 0, whc, wlc);
        #pragma unroll 1
        for (int kk = 0; kk < 8; kk++) {
          s8v bh[8], bl[8];
          gloadB(Bb, kk, bh, bl);
          s8v whn[2], wln[2];
          if (kk < 7) gloadW(Wb, kk + 1, whn, wln);    // W-only depth-1 prefetch
          #pragma unroll
          for (int mt = 0; mt < 2; mt++)
            #pragma unroll
            for (int bt = 0; bt < 8; bt++) {
              acc[mt][bt] = __builtin_amdgcn_mfma_f32_16x16x32_bf16(whc[mt], bh[bt], acc[mt][bt], 0, 0, 0);
              acc[mt][bt] = __builtin_amdgcn_mfma_f32_16x16x32_bf16(whc[mt], bl[bt], acc[mt][bt], 0, 0, 0);
              acc[mt][bt] = __builtin_amdgcn_mfma_f32_16x16x32_bf16(wlc[mt], bh[bt], acc[mt][bt], 0, 0, 0);
            }
          if (kk < 7) {
            whc[0] = whn[0]; whc[1] = whn[1];
            wlc[0] = wln[0]; wlc[1] = wln[1];
          }
        }
      } else {
        const float* Wsel = ((w < 4) ? (dir ? p.Wihr : p.Wih) : (dir ? p.Whhr : p.Whh))
                          + (size_t)layer * 4194304;
        int col0 = (w & 3) * 256 + lk * 8;
        const float* Wrow[2];
        Wrow[0] = Wsel + ((size_t)(((lr >> 3)) * 1024 + mb * 8 + (lr & 7))) * 1024 + col0;
        Wrow[1] = Wsel + ((size_t)((2 + (lr >> 3)) * 1024 + mb * 8 + (lr & 7))) * 1024 + col0;
        float4 ac[2][2];
        #pragma unroll
        for (int mt = 0; mt < 2; mt++) {
          ac[mt][0] = *(const float4*)(Wrow[mt]);
          ac[mt][1] = *(const float4*)(Wrow[mt] + 4);
        }
        #pragma unroll 1
        for (int kk = 0; kk < 8; kk++) {
          s8v bh[8], bl[8];
          gloadB(Bb, kk, bh, bl);
          float4 an[2][2];
          if (kk < 7) {
            #pragma unroll
            for (int mt = 0; mt < 2; mt++) {
              an[mt][0] = *(const float4*)(Wrow[mt] + (kk + 1) * 32);
              an[mt][1] = *(const float4*)(Wrow[mt] + (kk + 1) * 32 + 4);
            }
          }
          #pragma unroll
          for (int mt = 0; mt < 2; mt++) {
            s8v wh, wl;
            cvt8(ac[mt][0], ac[mt][1], wh, wl);
            #pragma unroll
            for (int bt = 0; bt < 8; bt++) {
              acc[mt][bt] = __builtin_amdgcn_mfma_f32_16x16x32_bf16(wh, bh[bt], acc[mt][bt], 0, 0, 0);
              acc[mt][bt] = __builtin_amdgcn_mfma_f32_16x16x32_bf16(wh, bl[bt], acc[mt][bt], 0, 0, 0);
              acc[mt][bt] = __builtin_amdgcn_mfma_f32_16x16x32_bf16(wl, bh[bt], acc[mt][bt], 0, 0, 0);
            }
          }
          if (kk < 7) {
            #pragma unroll
            for (int mt = 0; mt < 2; mt++) { ac[mt][0] = an[mt][0]; ac[mt][1] = an[mt][1]; }
          }
        }
      }

      // ---- in-block K reduction: 8 -> 4 -> 2 -> zs stage ----
      if (w >= 4) red_write(lds, w - 4, l, acc);
      __syncthreads();
      if (w < 4) red_add(lds, w, l, acc);
      __syncthreads();
      if (w == 2 || w == 3) red_write(lds, w - 2, l, acc);
      __syncthreads();
      if (w < 2) red_add(lds, w, l, acc);
      __syncthreads();
      if (w < 2) red_write(lds, w, l, acc);
      __syncthreads();
      float* zs = lds + 8192;                 // [2mt][16slot][128b]
      #pragma unroll
      for (int vi = 0; vi < 2; vi++) {
        int v = tid + vi * 512;
        f4v s = *(const f4v*)&lds[(size_t)v * 4];
        s += *(const f4v*)&lds[4096 + (size_t)v * 4];
        int frag = v >> 6, lane = v & 63;
        int mt = frag >> 3, bt = frag & 7;
        int s0 = (lane >> 4) * 4, bcol = bt * 16 + (lane & 15);
        #pragma unroll
        for (int r = 0; r < 4; r++)
          zs[mt * 2048 + (s0 + r) * 128 + bcol] = s[r];
      }
      __syncthreads();

      // ---- fused gates: thread = (b, 4 consecutive n); coalesced stores ----
      int ldg = layer * 2 + dir;
      if (tid < 256) {
        int b = tid & 127, q = tid >> 7;
        float* cp = p.c + ((((size_t)ldg * 128 + mb) * 128 + b) * 8 + q * 4);
        f4v cold = *(const f4v*)cp;
        f4v cnew;
        float hs[4];
        #pragma unroll
        for (int j = 0; j < 4; j++) {
          int nl = q * 4 + j;
          int n = mb * 8 + nl;
          float iv = zs[nl * 128 + b]              + p.bias[ldg * 4096 + n];
          float fv = zs[(nl + 8) * 128 + b]        + p.bias[ldg * 4096 + 1024 + n];
          float gv = zs[2048 + nl * 128 + b]       + p.bias[ldg * 4096 + 2048 + n];
          float ov = zs[2048 + (nl + 8) * 128 + b] + p.bias[ldg * 4096 + 3072 + n];
          float co = cold[j];
          float cn = sigmoid_stable(fv) * co + sigmoid_stable(iv) * tanhf(gv);
          float hn = sigmoid_stable(ov) * tanhf(cn);
          cnew[j] = cn;
          hs[j] = hn;
        }
        st_f4(cp, cnew);
        unsigned short hh[4], ll[4];
        #pragma unroll
        for (int j = 0; j < 4; j++) split_bf(hs[j], hh[j], ll[j]);
        int kt = layer * 32 + (mb >> 2);
        size_t off = ((size_t)(dir * 64 + kt) * 8 + (b >> 4)) * 1024
                   + ((size_t)((b & 15) + 16 * (mb & 3))) * 8 + q * 4;
        st_u2((unsigned*)(xpW + off),
              (unsigned)hh[0] | ((unsigned)hh[1] << 16),
              (unsigned)hh[2] | ((unsigned)hh[3] << 16));
        st_u2((unsigned*)(xpW + off + 512),
              (unsigned)ll[0] | ((unsigned)ll[1] << 16),
              (unsigned)ll[2] | ((unsigned)ll[3] << 16));
        if (layer == 1) {
          #pragma unroll
          for (int j = 0; j < 4; j++) {
            int n = mb * 8 + q * 4 + j;
            st_f(p.Ht + (size_t)dir * 131072 + (size_t)n * 128 + b, hs[j]);
          }
        }
      }
      ++nbar; gbar(p.bar, nbar, true);
    } // layer

    // ---- fc: fcz[kp][b][e] partials, 256 blocks = (16 et, 16 kp) ----
    {
      int et = bid & 15, kp = bid >> 4;
      int e0 = et * 64, k00 = kp * 128;
      float* in_s = lds;            // [128][36]
      float* w_s  = lds + 4608;     // [64][36]
      int e_sub = tid & 7, bg = tid >> 3, b0 = bg * 2;
      float accf[8][2];
      #pragma unroll
      for (int je = 0; je < 8; je++) { accf[je][0] = 0.f; accf[je][1] = 0.f; }
      for (int kc = 0; kc < 128; kc += 32) {
        #pragma unroll
        for (int i = 0; i < 2; i++) {
          int flat = tid + 512 * i, r = flat >> 3, f4i = flat & 7;
          float4 v = *(const float4*)(p.Ht + (size_t)r * 2048 + k00 + kc + f4i * 4);
          int sw = (f4i ^ (r >> 2)) & 7;
          *(float4*)&in_s[r * 36 + sw * 4] = v;
        }
        {
          int r = tid >> 3, f4i = tid & 7;
          *(float4*)&w_s[r * 36 + f4i * 4] =
              *(const float4*)(p.fcW + (size_t)(e0 + r) * 2048 + k00 + kc + f4i * 4);
        }
        __syncthreads();
        #pragma unroll
        for (int kq = 0; kq < 8; kq++) {
          int ksw = (kq ^ (bg >> 1)) & 7;
          float4 a0 = *(const float4*)&in_s[b0 * 36 + ksw * 4];
          float4 a1 = *(const float4*)&in_s[(b0 + 1) * 36 + ksw * 4];
          #pragma unroll
          for (int je = 0; je < 8; je++) {
            float4 w4 = *(const float4*)&w_s[(e_sub + 8 * je) * 36 + kq * 4];
            accf[je][0] += a0.x * w4.x + a0.y * w4.y + a0.z * w4.z + a0.w * w4.w;
            accf[je][1] += a1.x * w4.x + a1.y * w4.y + a1.z * w4.z + a1.w * w4.w;
          }
        }
        __syncthreads();
      }
      // stage to LDS transpose, then 64B-contiguous coherent stores
      #pragma unroll
      for (int je = 0; je < 8; je++) {
        lds[(b0    ) * 68 + e_sub + 8 * je] = accf[je][0];
        lds[(b0 + 1) * 68 + e_sub + 8 * je] = accf[je][1];
      }
      __syncthreads();
      {
        int row = tid >> 2, ch = tid & 3;
        float* gp = p.fcz + ((size_t)kp * 128 + row) * 1024 + e0 + ch * 16;
        #pragma unroll
        for (int i = 0; i < 4; i++)
          st_f4(gp + 4 * i, *(const f4v*)&lds[row * 68 + ch * 16 + 4 * i]);
      }
      ++nbar; gbar(p.bar, nbar, true);
    }

    // ---- final: logits, argmax, softmax, pack next x (blocks 0..127) ----
    if (bid < 128) {
      int b = bid;
      float* sval = lds;
      int*   sidx = (int*)(lds + 512);
      float* ssum = lds + 1024;
      bool end = (ended_reg != 0);
      int e2 = tid * 2;
      float vx = p.fcb[e2], vy = p.fcb[e2 + 1];
      #pragma unroll
      for (int q = 0; q < 16; q++) {
        const float* f = &p.fcz[((size_t)q * 128 + b) * 1024 + e2];
        vx += f[0]; vy += f[1];
      }
      if (end) { vx = (e2 == EOSL) ? 1.f : 0.f; vy = (e2 + 1 == EOSL) ? 1.f : 0.f; }
      float bv; int bi;
      if (vy > vx) { bv = vy; bi = e2 + 1; } else { bv = vx; bi = e2; }
      sval[tid] = bv; sidx[tid] = bi;
      __syncthreads();
      for (int s = 256; s > 0; s >>= 1) {
        if (tid < s) {
          float ov = sval[tid + s]; int oi = sidx[tid + s];
          if (ov > sval[tid] || (ov == sval[tid] && oi < sidx[tid])) { sval[tid] = ov; sidx[tid] = oi; }
        }
        __syncthreads();
      }
      float m = sval[0]; int label = sidx[0];
      {
        int k0 = tid * 2;
        float ex = p.emb[(size_t)label * 1024 + k0];
        float ey = p.emb[(size_t)label * 1024 + k0 + 1];
        size_t off = ((size_t)(k0 >> 5) * 8 + (b >> 4)) * 1024
                   + ((b & 15) + 16 * ((k0 >> 3) & 3)) * 8 + (k0 & 7);
        unsigned short h0, l0, h1, l1;
        split_bf(ex, h0, l0); split_bf(ey, h1, l1);
        st_u32((unsigned*)(p.xpx + off),       (unsigned)h0 | ((unsigned)h1 << 16));
        st_u32((unsigned*)(p.xpx + off + 512), (unsigned)l0 | ((unsigned)l1 << 16));
      }
      float ex0 = expf(vx - m), ex1 = expf(vy - m);
      ssum[tid] = ex0 + ex1;
      __syncthreads();
      for (int s = 256; s > 0; s >>= 1) { if (tid < s) ssum[tid] += ssum[tid + s]; __syncthreads(); }
      float inv = 1.f / ssum[0];
      float* orow = p.out + ((size_t)b * NT + t) * NE + e2;
      st_f2(orow, ex0 * inv, ex1 * inv);
      ended_reg = (end || label == EOSL) ? 1 : 0;
    }
    ++nbar; gbar(p.bar, nbar, true);
  } // t
}

extern "C" void kernel_launch(void* const* d_in, const int* in_sizes, int n_in,
                              void* d_out, int out_size, void* d_ws, size_t ws_size,
                              hipStream_t stream)
{
  const int*   yy    = (const int*)d_in[0];
  const float* h_t   = (const float*)d_in[1];
  const float* h_tr  = (const float*)d_in[2];
  const float* emb   = (const float*)d_in[4];
  const float* W_ih  = (const float*)d_in[5];
  const float* W_hh  = (const float*)d_in[6];
  const float* b_ih  = (const float*)d_in[7];
  const float* b_hh  = (const float*)d_in[8];
  const float* W_ihr = (const float*)d_in[9];
  const float* W_hhr = (const float*)d_in[10];
  const float* b_ihr = (const float*)d_in[11];
  const float* b_hhr = (const float*)d_in[12];
  const float* c0    = (const float*)d_in[13];
  const float* c0r   = (const float*)d_in[14];
  const float* fc_W  = (const float*)d_in[15];
  const float* fc_b  = (const float*)d_in[16];
  float* out = (float*)d_out;

  float* ws = (float*)d_ws;
  KP p;
  p.c     = ws + C_OFF;
  p.Ht    = ws + HT_OFF;
  p.fcz   = ws + FCZ_OFF;
  p.bias  = ws + BIAS_OFF;
  p.bar   = (int*)(ws + BAR_OFF);
  p.xph   = (unsigned short*)(ws + XPH_OFF);
  p.xpx   = (unsigned short*)(ws + XPX_OFF);
  p.WP    = (const unsigned short*)(ws + WP_OFF);
  p.Wih = W_ih; p.Whh = W_hh; p.Wihr = W_ihr; p.Whhr = W_hhr;
  p.fcW = fc_W; p.fcb = fc_b; p.emb = emb;
  p.out = out;
  bool packed = ws_size >= TOTAL_PACK_F * sizeof(float);

  k_init<<<2048, 256, 0, stream>>>(yy, h_t, h_tr, c0, c0r, b_ih, b_hh, b_ihr, b_hhr,
                                   emb, p.xph, p.xpx, p.c, (float*)p.bias, p.bar);
  if (packed)
    k_packW<<<16384, 256, 0, stream>>>(W_ih, W_hh, W_ihr, W_hhr,
                                       (unsigned short*)p.WP);

  if (packed) k_all<1><<<256, 512, 0, stream>>>(p);
  else        k_all<0><<<256, 512, 0, stream>>>(p);
}

// Round 11
// 22782.756 us; speedup vs baseline: 3.9343x; 2.0520x over previous
//
#include <hip/hip_runtime.h>
#include <math.h>

// B=128, T=256, H=E=1024, L=2, EOS=1
#define NB 128
#define NT 256
#define NH 1024
#define NE 1024
#define G4 4096
#define EOSL 1

// ---------------- workspace layout (float units) ----------------
#define C_OFF    ((size_t)0)          // c [(l*2+dir)][mb 128][b 128][nl 8] = 524,288
#define HT_OFF   ((size_t)524288)     // Ht [2dir][1024 n][128 b] = 262,144
#define FCZ_OFF  ((size_t)786432)     // fcz [8 kp][128 b][1024 e] = 1,048,576
#define BIAS_OFF ((size_t)1835008)    // 16,384
#define END_OFF  ((size_t)1851392)    // 128
#define XPH_OFF  ((size_t)1851520)    // 2 parity x 524,288 f
#define XPX_OFF  ((size_t)2900096)    // 131,072 f
#define WP_OFF   ((size_t)3031168)    // 33,554,432 f
#define TOTAL_MIN_F  ((size_t)3031168)
#define TOTAL_PACK_F ((size_t)36585600)   // ~146.3 MB

typedef __attribute__((ext_vector_type(8))) short s8v;   // 8 bf16 for MFMA A/B
typedef __attribute__((ext_vector_type(4))) float f4v;   // MFMA C/D
typedef __attribute__((ext_vector_type(2))) unsigned u2v;

__device__ __forceinline__ float sigmoid_stable(float x) {
  if (x >= 0.f) return 1.f / (1.f + expf(-x));
  float ex = expf(x);
  return ex / (1.f + ex);
}
__device__ __forceinline__ void add4(float4& d, const float4 a) {
  d.x += a.x; d.y += a.y; d.z += a.z; d.w += a.w;
}
__device__ __forceinline__ unsigned short bf_rne(float x) {
  unsigned u = __float_as_uint(x);
  return (unsigned short)((u + 0x7FFFu + ((u >> 16) & 1u)) >> 16);
}
__device__ __forceinline__ void split_bf(float x, unsigned short& h, unsigned short& l) {
  unsigned u = __float_as_uint(x);
  unsigned hb = (u + 0x7FFFu + ((u >> 16) & 1u)) >> 16;
  h = (unsigned short)hb;
  float r = x - __uint_as_float(hb << 16);   // exact
  l = bf_rne(r);
}
__device__ __forceinline__ void cvt8(float4 a0, float4 a1, s8v& hi, s8v& lo)
{
  const float v[8] = {a0.x, a0.y, a0.z, a0.w, a1.x, a1.y, a1.z, a1.w};
  #pragma unroll
  for (int j = 0; j < 8; j++) {
    unsigned short h, l; split_bf(v[j], h, l);
    hi[j] = (short)h; lo[j] = (short)l;
  }
}

// frag layouts (verified rounds 0-9):
//  B (acts): lane l holds B[k=(l>>4)*8+r][b=l&15]; frag = 512 hi + 512 lo shorts
//  A (wgts): lane l holds A[slot=l&15][k=(l>>4)*8+r]
//  cell WP gate-interleaved mtiles: mtile=mb*2+half; slot s -> m = gate*1024+
//  mb*8+(s&7), gate = half*2+(s>>3).  C/D: col=lane&15 (b), row slot=(lane>>4)*4+reg.
// NOTE: the reference FC input is wh = concat(h,hr).T.reshape(B,-1) — a SHUFFLE
//  (wh[b,e] = h_concat[e%128][b*16+e//128]), NOT per-batch concat. The fp32 k_fc
//  implements it by reading Ht[2dir][n][b] as flat 2048-float rows (verified R0-R3).

// ---------------- init ----------------
__global__ void k_init(const int* yy, const float* h_t, const float* h_tr,
                       const float* c0, const float* c0r,
                       const float* b_ih, const float* b_hh,
                       const float* b_ihr, const float* b_hhr,
                       const float* emb,
                       unsigned short* xph, unsigned short* xpx,
                       float* call, float* bias, int* ended)
{
  int idx = blockIdx.x * 256 + threadIdx.x;   // 2048 blocks -> 524288
  if (idx < 2 * 2048 * 128) {                 // XPH parity-0
    int dir = idx / (2048 * 128); int rem = idx % (2048 * 128);
    int row = rem >> 7, b = rem & 127;
    int l = row >> 10, n = row & 1023;
    const float* src = dir ? h_tr : h_t;
    float v = src[((size_t)l * 128 + b) * 1024 + n];
    unsigned short h, lo; split_bf(v, h, lo);
    size_t off = ((size_t)(dir * 64 + (row >> 5)) * 8 + (b >> 4)) * 1024
               + ((b & 15) + 16 * ((n >> 3) & 3)) * 8 + (n & 7);
    xph[off] = h; xph[off + 512] = lo;
  }
  if (idx < 4 * 1024 * 128) {                 // c [(ld)][mb][b][nl]
    int ld = idx / (1024 * 128); int l = ld >> 1;
    int rem = idx % (1024 * 128);
    int mb = rem >> 10, nl = rem & 7;
    const float* cs = (ld & 1) ? c0r : c0;
    call[idx] = cs[l * 1024 + mb * 8 + nl];
  }
  if (idx < 4 * 4096) {                       // bias[(l*2+dir)][m]
    int ld = idx / 4096; int l = ld >> 1, dir = ld & 1;
    int m = idx & 4095;
    bias[idx] = (dir ? b_ihr : b_ih)[l * 4096 + m] + (dir ? b_hhr : b_hh)[l * 4096 + m];
  }
  if (idx < 128 * 1024) {                     // XPX: x0 = emb[yy[:,0]]
    int b = idx >> 10, k = idx & 1023;
    int e = yy[b * NT];
    float v = emb[(size_t)e * 1024 + k];
    unsigned short h, lo; split_bf(v, h, lo);
    size_t off = ((size_t)(k >> 5) * 8 + (b >> 4)) * 1024
               + ((b & 15) + 16 * ((k >> 3) & 3)) * 8 + (k & 7);
    xpx[off] = h; xpx[off + 512] = lo;
  }
  if (idx < NB) ended[idx] = 0;
}

// ---------------- one-time weight pre-split (gate-interleaved mtiles) --------
__global__ void k_packW(const float* W_ih, const float* W_hh,
                        const float* W_ihr, const float* W_hhr,
                        unsigned short* WP)
{
  int idx = blockIdx.x * 256 + threadIdx.x;   // 16384 blocks -> 4,194,304
  int l = idx & 63;
  int frag = idx >> 6;
  int ktile = frag & 63;
  int mtile = (frag >> 6) & 255;
  int ld = frag >> 14;
  int layer = ld >> 1, dir = ld & 1;
  int s = l & 15;
  int mbb = mtile >> 1, half = mtile & 1;
  int gate = half * 2 + (s >> 3);
  int m = gate * 1024 + mbb * 8 + (s & 7);
  int kg = ktile * 32 + (l >> 4) * 8;
  const float* base;
  if (kg < 1024) base = (dir ? W_ihr : W_ih) + ((size_t)layer * 4096 + m) * 1024 + kg;
  else           base = (dir ? W_hhr : W_hh) + ((size_t)layer * 4096 + m) * 1024 + (kg - 1024);
  float4 a0 = *(const float4*)base, a1 = *(const float4*)(base + 4);
  s8v hi, lo; cvt8(a0, a1, hi, lo);
  unsigned short* outp = WP + (size_t)frag * 1024 + l * 8;
  *(s8v*)outp = hi;
  *(s8v*)(outp + 512) = lo;
}

// ---------------- reduction-tree helpers (verified round 3) ------------------
__device__ __forceinline__ void red_write(float* red, int slot, int l, const f4v (&acc)[2][8])
{
  #pragma unroll
  for (int mt = 0; mt < 2; mt++)
    #pragma unroll
    for (int bt = 0; bt < 8; bt++)
      *(f4v*)&red[(size_t)slot * 4096 + (mt * 8 + bt) * 256 + l * 4] = acc[mt][bt];
}
__device__ __forceinline__ void red_add(const float* red, int slot, int l, f4v (&acc)[2][8])
{
  #pragma unroll
  for (int mt = 0; mt < 2; mt++)
    #pragma unroll
    for (int bt = 0; bt < 8; bt++)
      acc[mt][bt] += *(const f4v*)&red[(size_t)slot * 4096 + (mt * 8 + bt) * 256 + l * 4];
}
__device__ __forceinline__ void gloadW(const unsigned short* Wb, int kk,
                                       s8v (&h)[2], s8v (&lo)[2])
{
  #pragma unroll
  for (int mt = 0; mt < 2; mt++) {
    const unsigned short* q = Wb + ((size_t)(mt * 64 + kk) << 10);
    h[mt] = *(const s8v*)q; lo[mt] = *(const s8v*)(q + 512);
  }
}
__device__ __forceinline__ void gloadB(const unsigned short* Bb, int kk,
                                       s8v (&h)[8], s8v (&lo)[8])
{
  #pragma unroll
  for (int bt = 0; bt < 8; bt++) {
    const unsigned short* q = Bb + ((size_t)(kk * 8 + bt) << 10);
    h[bt] = *(const s8v*)q; lo[bt] = *(const s8v*)(q + 512);
  }
}

// gemm core: acc[2][8] += W(K256-chunk) * B ; PACKED uses pre-split frags
template<int PACKED>
__device__ __forceinline__ void gemm_k256(f4v (&acc)[2][8],
                                          const unsigned short* Wb,
                                          const float* Wrow0, const float* Wrow1,
                                          const unsigned short* Bb)
{
  if (PACKED) {
    s8v whc[2], wlc[2];
    gloadW(Wb, 0, whc, wlc);
    #pragma unroll 1
    for (int kk = 0; kk < 8; kk++) {
      s8v bh[8], bl[8];
      gloadB(Bb, kk, bh, bl);
      s8v whn[2], wln[2];
      if (kk < 7) gloadW(Wb, kk + 1, whn, wln);      // W-only depth-1 prefetch
      #pragma unroll
      for (int mt = 0; mt < 2; mt++)
        #pragma unroll
        for (int bt = 0; bt < 8; bt++) {
          acc[mt][bt] = __builtin_amdgcn_mfma_f32_16x16x32_bf16(whc[mt], bh[bt], acc[mt][bt], 0, 0, 0);
          acc[mt][bt] = __builtin_amdgcn_mfma_f32_16x16x32_bf16(whc[mt], bl[bt], acc[mt][bt], 0, 0, 0);
          acc[mt][bt] = __builtin_amdgcn_mfma_f32_16x16x32_bf16(wlc[mt], bh[bt], acc[mt][bt], 0, 0, 0);
        }
      if (kk < 7) {
        whc[0] = whn[0]; whc[1] = whn[1];
        wlc[0] = wln[0]; wlc[1] = wln[1];
      }
    }
  } else {
    const float* Wrow[2] = { Wrow0, Wrow1 };
    float4 ac[2][2];
    #pragma unroll
    for (int mt = 0; mt < 2; mt++) {
      ac[mt][0] = *(const float4*)(Wrow[mt]);
      ac[mt][1] = *(const float4*)(Wrow[mt] + 4);
    }
    #pragma unroll 1
    for (int kk = 0; kk < 8; kk++) {
      s8v bh[8], bl[8];
      gloadB(Bb, kk, bh, bl);
      float4 an[2][2];
      if (kk < 7) {
        #pragma unroll
        for (int mt = 0; mt < 2; mt++) {
          an[mt][0] = *(const float4*)(Wrow[mt] + (kk + 1) * 32);
          an[mt][1] = *(const float4*)(Wrow[mt] + (kk + 1) * 32 + 4);
        }
      }
      #pragma unroll
      for (int mt = 0; mt < 2; mt++) {
        s8v wh, wl;
        cvt8(ac[mt][0], ac[mt][1], wh, wl);
        #pragma unroll
        for (int bt = 0; bt < 8; bt++) {
          acc[mt][bt] = __builtin_amdgcn_mfma_f32_16x16x32_bf16(wh, bh[bt], acc[mt][bt], 0, 0, 0);
          acc[mt][bt] = __builtin_amdgcn_mfma_f32_16x16x32_bf16(wh, bl[bt], acc[mt][bt], 0, 0, 0);
          acc[mt][bt] = __builtin_amdgcn_mfma_f32_16x16x32_bf16(wl, bh[bt], acc[mt][bt], 0, 0, 0);
        }
      }
      if (kk < 7) {
        #pragma unroll
        for (int mt = 0; mt < 2; mt++) { ac[mt][0] = an[mt][0]; ac[mt][1] = an[mt][1]; }
      }
    }
  }
}

// shared epilogue: tree-reduce 8 wave partials into zs = lds+8192 ([2mt][16s][128b])
__device__ __forceinline__ void reduce_to_zs(float* lds, int tid, int l, int w,
                                             f4v (&acc)[2][8])
{
  if (w >= 4) red_write(lds, w - 4, l, acc);
  __syncthreads();
  if (w < 4) red_add(lds, w, l, acc);
  __syncthreads();
  if (w == 2 || w == 3) red_write(lds, w - 2, l, acc);
  __syncthreads();
  if (w < 2) red_add(lds, w, l, acc);
  __syncthreads();
  if (w < 2) red_write(lds, w, l, acc);
  __syncthreads();
  float* zs = lds + 8192;
  #pragma unroll
  for (int vi = 0; vi < 2; vi++) {
    int v = tid + vi * 512;
    f4v s = *(const f4v*)&lds[(size_t)v * 4];
    s += *(const f4v*)&lds[4096 + (size_t)v * 4];
    int frag = v >> 6, lane = v & 63;
    int mt = frag >> 3, bt = frag & 7;
    int s0 = (lane >> 4) * 4, bcol = bt * 16 + (lane & 15);
    #pragma unroll
    for (int r = 0; r < 4; r++)
      zs[mt * 2048 + (s0 + r) * 128 + bcol] = s[r];
  }
  __syncthreads();
}

struct CellP {
  const unsigned short* WP;
  const float* Wih; const float* Whh; const float* Wihr; const float* Whhr;
  const float* bias; float* c; const unsigned short* xpx; float* Ht;
};

// ---------------- fused cell GEMM + gates, one kernel per layer --------------
// grid (128 mb, 2 dir), 512 thr; block = 32 m-rows (gate-interleaved) x 128 b x K=2048
template<int LAYER, int PACKED>
__global__ __launch_bounds__(512, 2) void k_cell(CellP p, const unsigned short* xpR,
                                                 unsigned short* xpW)
{
  __shared__ __align__(16) float lds[16384];           // 64 KB
  const int mb = blockIdx.x, dir = blockIdx.y, tid = threadIdx.x;
  const int l = tid & 63, w = tid >> 6;                // w = K-chunk 0..7
  const int lr = l & 15, lk = l >> 4;

  const unsigned short* Bb;
  if (LAYER == 0)
    Bb = (w < 4) ? p.xpx + (size_t)w * 65536
                 : xpR + (size_t)(dir * 64 + (w - 4) * 8) * 8192;
  else
    Bb = (w < 4) ? xpW + (size_t)(dir * 64 + w * 8) * 8192
                 : xpR + (size_t)(dir * 64 + 32 + (w - 4) * 8) * 8192;
  Bb += l * 8;

  f4v acc[2][8];
  #pragma unroll
  for (int mt = 0; mt < 2; mt++)
    #pragma unroll
    for (int bt = 0; bt < 8; bt++)
      acc[mt][bt] = (f4v)(0.0f);

  if (PACKED) {
    const unsigned short* Wb = p.WP + (size_t)(LAYER * 2 + dir) * 16777216ULL
        + (((size_t)(mb * 2) * 64 + (size_t)w * 8) << 10) + l * 8;
    gemm_k256<1>(acc, Wb, nullptr, nullptr, Bb);
  } else {
    const float* Wsel = ((w < 4) ? (dir ? p.Wihr : p.Wih) : (dir ? p.Whhr : p.Whh))
                      + (size_t)LAYER * 4194304;
    int col0 = (w & 3) * 256 + lk * 8;
    const float* Wr0 = Wsel + ((size_t)(((lr >> 3)) * 1024 + mb * 8 + (lr & 7))) * 1024 + col0;
    const float* Wr1 = Wsel + ((size_t)((2 + (lr >> 3)) * 1024 + mb * 8 + (lr & 7))) * 1024 + col0;
    gemm_k256<0>(acc, nullptr, Wr0, Wr1, Bb);
  }

  reduce_to_zs(lds, tid, l, w, acc);
  float* zs = lds + 8192;

  // fused gates: thread = (b, 4 consecutive n); plain cached stores
  int ldg = LAYER * 2 + dir;
  if (tid < 256) {
    int b = tid & 127, q = tid >> 7;
    float* cp = p.c + ((((size_t)ldg * 128 + mb) * 128 + b) * 8 + q * 4);
    f4v cold = *(const f4v*)cp;
    f4v cnew;
    float hs[4];
    #pragma unroll
    for (int j = 0; j < 4; j++) {
      int nl = q * 4 + j;
      int n = mb * 8 + nl;
      float iv = zs[nl * 128 + b]              + p.bias[ldg * 4096 + n];
      float fv = zs[(nl + 8) * 128 + b]        + p.bias[ldg * 4096 + 1024 + n];
      float gv = zs[2048 + nl * 128 + b]       + p.bias[ldg * 4096 + 2048 + n];
      float ov = zs[2048 + (nl + 8) * 128 + b] + p.bias[ldg * 4096 + 3072 + n];
      float co = cold[j];
      float cn = sigmoid_stable(fv) * co + sigmoid_stable(iv) * tanhf(gv);
      float hn = sigmoid_stable(ov) * tanhf(cn);
      cnew[j] = cn;
      hs[j] = hn;
    }
    *(f4v*)cp = cnew;
    unsigned short hh[4], ll[4];
    #pragma unroll
    for (int j = 0; j < 4; j++) split_bf(hs[j], hh[j], ll[j]);
    int kt = LAYER * 32 + (mb >> 2);
    size_t off = ((size_t)(dir * 64 + kt) * 8 + (b >> 4)) * 1024
               + ((size_t)((b & 15) + 16 * (mb & 3))) * 8 + q * 4;
    u2v vh; vh.x = (unsigned)hh[0] | ((unsigned)hh[1] << 16);
            vh.y = (unsigned)hh[2] | ((unsigned)hh[3] << 16);
    u2v vl; vl.x = (unsigned)ll[0] | ((unsigned)ll[1] << 16);
            vl.y = (unsigned)ll[2] | ((unsigned)ll[3] << 16);
    *(u2v*)(xpW + off) = vh;
    *(u2v*)(xpW + off + 512) = vl;
    if (LAYER == 1) {
      #pragma unroll
      for (int j = 0; j < 4; j++) {
        int n = mb * 8 + q * 4 + j;
        p.Ht[(size_t)dir * 131072 + (size_t)n * 128 + b] = hs[j];
      }
    }
  }
}

// ---------------- FC GEMM (fp32, verified R0-R3): fcz[kp][b][e] partials -----
// Implements the reference's wh shuffle by reading Ht[2dir][n][b] as flat rows.
__global__ __launch_bounds__(256) void k_fc(const float* Ht, const float* fc_W, float* fcz)
{
  int et = blockIdx.x, kp = blockIdx.y;
  int e0 = et * 64;
  int k00 = kp * 256;
  __shared__ __align__(16) float in_s[128][36];
  __shared__ __align__(16) float w_s[64][36];
  int t = threadIdx.x, e_sub = t & 7, bg = t >> 3, b0 = bg * 4;
  float acc[8][4] = {};
  for (int kc = 0; kc < 256; kc += 32) {
    #pragma unroll
    for (int i = 0; i < 4; i++) {
      int flat = t + 256 * i, r = flat >> 3, f4i = flat & 7;
      const float* row = Ht + (r >= 64 ? (size_t)NH * NB + (size_t)(r - 64) * 2048
                                       : (size_t)r * 2048);
      float4 v = *(const float4*)(row + k00 + kc + f4i * 4);
      int sw = (f4i ^ (r >> 2)) & 7;
      *(float4*)&in_s[r][sw * 4] = v;
    }
    #pragma unroll
    for (int i = 0; i < 2; i++) {
      int flat = t + 256 * i, r = flat >> 3, f4i = flat & 7;
      *(float4*)&w_s[r][f4i * 4] =
          *(const float4*)(fc_W + (size_t)(e0 + r) * 2048 + k00 + kc + f4i * 4);
    }
    __syncthreads();
    #pragma unroll
    for (int kq = 0; kq < 8; kq++) {
      int ksw = (kq ^ bg) & 7;
      float4 a4[4];
      #pragma unroll
      for (int ib = 0; ib < 4; ib++) a4[ib] = *(const float4*)&in_s[b0 + ib][ksw * 4];
      float4 w4[8];
      #pragma unroll
      for (int je = 0; je < 8; je++) w4[je] = *(const float4*)&w_s[e_sub + 8 * je][kq * 4];
      #pragma unroll
      for (int je = 0; je < 8; je++)
        #pragma unroll
        for (int ib = 0; ib < 4; ib++)
          acc[je][ib] += a4[ib].x * w4[je].x + a4[ib].y * w4[je].y +
                         a4[ib].z * w4[je].z + a4[ib].w * w4[je].w;
    }
    __syncthreads();
  }
  for (int je = 0; je < 8; je++) {
    int e = e0 + e_sub + 8 * je;
    for (int ib = 0; ib < 4; ib++)
      fcz[((size_t)kp * NB + b0 + ib) * NE + e] = acc[je][ib];
  }
}

// ---------------- finalize: logits, override, argmax, pack next x, softmax ---
__global__ void k_final(const float* fcz, const float* fc_b, int* ended,
                        float* out, int tstep, const float* emb, unsigned short* xpx)
{
  int b = blockIdx.x;
  int t = threadIdx.x;
  __shared__ float sval[256];
  __shared__ int   sidx[256];
  __shared__ float ssum[256];
  bool end = (ended[b] != 0);
  float v[4];
  int e_base = t * 4;
  float4 vv = *(const float4*)&fc_b[e_base];
  #pragma unroll
  for (int p = 0; p < 8; p++)
    add4(vv, *(const float4*)&fcz[((size_t)p * NB + b) * NE + e_base]);
  v[0] = vv.x; v[1] = vv.y; v[2] = vv.z; v[3] = vv.w;
  if (end) {
    #pragma unroll
    for (int j = 0; j < 4; j++) v[j] = (e_base + j == EOSL) ? 1.f : 0.f;
  }
  float bv = v[0]; int bi = e_base;
  #pragma unroll
  for (int j = 1; j < 4; j++) if (v[j] > bv) { bv = v[j]; bi = e_base + j; }
  sval[t] = bv; sidx[t] = bi;
  __syncthreads();
  for (int s = 128; s > 0; s >>= 1) {
    if (t < s) {
      float ov = sval[t + s]; int oi = sidx[t + s];
      if (ov > sval[t] || (ov == sval[t] && oi < sidx[t])) { sval[t] = ov; sidx[t] = oi; }
    }
    __syncthreads();
  }
  float m = sval[0]; int label = sidx[0];
  {
    int k0 = t * 4;
    float4 e4 = *(const float4*)(emb + (size_t)label * 1024 + k0);
    size_t off = ((size_t)(k0 >> 5) * 8 + (b >> 4)) * 1024
               + ((b & 15) + 16 * ((k0 >> 3) & 3)) * 8 + (k0 & 7);
    ushort4 h4, l4;
    unsigned short hh, ll;
    split_bf(e4.x, hh, ll); h4.x = hh; l4.x = ll;
    split_bf(e4.y, hh, ll); h4.y = hh; l4.y = ll;
    split_bf(e4.z, hh, ll); h4.z = hh; l4.z = ll;
    split_bf(e4.w, hh, ll); h4.w = hh; l4.w = ll;
    *(ushort4*)(xpx + off) = h4;
    *(ushort4*)(xpx + off + 512) = l4;
  }
  float ls = 0.f;
  #pragma unroll
  for (int j = 0; j < 4; j++) { v[j] = expf(v[j] - m); ls += v[j]; }
  ssum[t] = ls;
  __syncthreads();
  for (int s = 128; s > 0; s >>= 1) { if (t < s) ssum[t] += ssum[t + s]; __syncthreads(); }
  float inv = 1.f / ssum[0];
  float* orow = out + ((size_t)b * NT + tstep) * NE + e_base;
  #pragma unroll
  for (int j = 0; j < 4; j++) orow[j] = v[j] * inv;
  if (t == 0) ended[b] = (end || label == EOSL) ? 1 : 0;
}

extern "C" void kernel_launch(void* const* d_in, const int* in_sizes, int n_in,
                              void* d_out, int out_size, void* d_ws, size_t ws_size,
                              hipStream_t stream)
{
  const int*   yy    = (const int*)d_in[0];
  const float* h_t   = (const float*)d_in[1];
  const float* h_tr  = (const float*)d_in[2];
  const float* emb   = (const float*)d_in[4];
  const float* W_ih  = (const float*)d_in[5];
  const float* W_hh  = (const float*)d_in[6];
  const float* b_ih  = (const float*)d_in[7];
  const float* b_hh  = (const float*)d_in[8];
  const float* W_ihr = (const float*)d_in[9];
  const float* W_hhr = (const float*)d_in[10];
  const float* b_ihr = (const float*)d_in[11];
  const float* b_hhr = (const float*)d_in[12];
  const float* c0    = (const float*)d_in[13];
  const float* c0r   = (const float*)d_in[14];
  const float* fc_W  = (const float*)d_in[15];
  const float* fc_b  = (const float*)d_in[16];
  float* out = (float*)d_out;

  float* ws = (float*)d_ws;
  float* call = ws + C_OFF;
  float* Ht   = ws + HT_OFF;
  float* fcz  = ws + FCZ_OFF;
  float* bias = ws + BIAS_OFF;
  int* ended  = (int*)(ws + END_OFF);
  unsigned short* xph = (unsigned short*)(ws + XPH_OFF);
  unsigned short* xpx = (unsigned short*)(ws + XPX_OFF);
  unsigned short* WP  = (unsigned short*)(ws + WP_OFF);
  bool packed = ws_size >= TOTAL_PACK_F * sizeof(float);

  k_init<<<2048, 256, 0, stream>>>(yy, h_t, h_tr, c0, c0r, b_ih, b_hh, b_ihr, b_hhr,
                                   emb, xph, xpx, call, bias, ended);
  if (packed)
    k_packW<<<16384, 256, 0, stream>>>(W_ih, W_hh, W_ihr, W_hhr, WP);

  CellP cp;
  cp.WP = WP;
  cp.Wih = W_ih; cp.Whh = W_hh; cp.Wihr = W_ihr; cp.Whhr = W_hhr;
  cp.bias = bias; cp.c = call; cp.xpx = xpx; cp.Ht = Ht;

  for (int t = 0; t < NT; t++) {
    const unsigned short* xpR = xph + (size_t)(t & 1) * 1048576;
    unsigned short* xpW = xph + (size_t)((t & 1) ^ 1) * 1048576;
    if (packed) {
      k_cell<0, 1><<<dim3(128, 2), 512, 0, stream>>>(cp, xpR, xpW);
      k_cell<1, 1><<<dim3(128, 2), 512, 0, stream>>>(cp, xpR, xpW);
    } else {
      k_cell<0, 0><<<dim3(128, 2), 512, 0, stream>>>(cp, xpR, xpW);
      k_cell<1, 0><<<dim3(128, 2), 512, 0, stream>>>(cp, xpR, xpW);
    }
    k_fc<<<dim3(16, 8), 256, 0, stream>>>(Ht, fc_W, fcz);
    k_final<<<128, 256, 0, stream>>>(fcz, fc_b, ended, out, t, emb, xpx);
  }
}

// Round 12
// 21247.845 us; speedup vs baseline: 4.2185x; 1.0722x over previous
//
#include <hip/hip_runtime.h>
#include <math.h>

// B=128, T=256, H=E=1024, L=2, EOS=1
#define NB 128
#define NT 256
#define NH 1024
#define NE 1024
#define G4 4096
#define EOSL 1

// ---------------- workspace layout (float units) ----------------
#define C_OFF    ((size_t)0)          // c [(l*2+dir)][n 1024][b 128] = 524,288
#define HT_OFF   ((size_t)524288)     // Ht [2dir][1024 n][128 b] = 262,144
#define FCZ_OFF  ((size_t)786432)     // fcz [16 kp][128 b][1024 e] = 2,097,152
#define BIAS_OFF ((size_t)2883584)    // 16,384
#define END_OFF  ((size_t)2899968)    // 128
#define XPH_OFF  ((size_t)2900096)    // 2 parity x 524,288 f
#define XPX_OFF  ((size_t)3948672)    // 131,072 f
#define WP_OFF   ((size_t)4079744)    // 33,554,432 f
#define TOTAL_MIN_F  ((size_t)4079744)
#define TOTAL_PACK_F ((size_t)37634176)   // ~150.5 MB

typedef __attribute__((ext_vector_type(8))) short s8v;   // 8 bf16 for MFMA A/B
typedef __attribute__((ext_vector_type(4))) float f4v;   // MFMA C/D

__device__ __forceinline__ float sigmoid_stable(float x) {
  if (x >= 0.f) return 1.f / (1.f + expf(-x));
  float ex = expf(x);
  return ex / (1.f + ex);
}
__device__ __forceinline__ void add4(float4& d, const float4 a) {
  d.x += a.x; d.y += a.y; d.z += a.z; d.w += a.w;
}
__device__ __forceinline__ unsigned short bf_rne(float x) {
  unsigned u = __float_as_uint(x);
  return (unsigned short)((u + 0x7FFFu + ((u >> 16) & 1u)) >> 16);
}
__device__ __forceinline__ void split_bf(float x, unsigned short& h, unsigned short& l) {
  unsigned u = __float_as_uint(x);
  unsigned hb = (u + 0x7FFFu + ((u >> 16) & 1u)) >> 16;
  h = (unsigned short)hb;
  float r = x - __uint_as_float(hb << 16);   // exact
  l = bf_rne(r);
}
__device__ __forceinline__ void cvt8(float4 a0, float4 a1, s8v& hi, s8v& lo)
{
  const float v[8] = {a0.x, a0.y, a0.z, a0.w, a1.x, a1.y, a1.z, a1.w};
  #pragma unroll
  for (int j = 0; j < 8; j++) {
    unsigned short h, l; split_bf(v[j], h, l);
    hi[j] = (short)h; lo[j] = (short)l;
  }
}

// frag layouts (verified rounds 0-11):
//  B (acts): lane l holds B[k=(l>>4)*8+r][b=l&15]; frag = 512 hi + 512 lo shorts
//  A (wgts): lane l holds A[slot=l&15][k=(l>>4)*8+r]
//  NEW cell WP 16-row mtiles: mq in [0,256) covers n in [mq*4, mq*4+4);
//  slot s -> m = gate*1024 + mq*4 + (s&3), gate = s>>2.
//  C/D: col=lane&15 (b), row slot=(lane>>4)*4+reg.
// Reference FC input wh = concat(h,hr).T.reshape(B,-1) is a SHUFFLE
//  (wh[b,e] = h_concat[e%128][b*16+e//128]); k_fc implements it by reading
//  Ht[2dir][n][b] as flat 2048-float rows (verified R0-R3, R11).

// ---------------- init ----------------
__global__ void k_init(const int* yy, const float* h_t, const float* h_tr,
                       const float* c0, const float* c0r,
                       const float* b_ih, const float* b_hh,
                       const float* b_ihr, const float* b_hhr,
                       const float* emb,
                       unsigned short* xph, unsigned short* xpx,
                       float* call, float* bias, int* ended)
{
  int idx = blockIdx.x * 256 + threadIdx.x;   // 2048 blocks -> 524288
  if (idx < 2 * 2048 * 128) {                 // XPH parity-0
    int dir = idx / (2048 * 128); int rem = idx % (2048 * 128);
    int row = rem >> 7, b = rem & 127;
    int l = row >> 10, n = row & 1023;
    const float* src = dir ? h_tr : h_t;
    float v = src[((size_t)l * 128 + b) * 1024 + n];
    unsigned short h, lo; split_bf(v, h, lo);
    size_t off = ((size_t)(dir * 64 + (row >> 5)) * 8 + (b >> 4)) * 1024
               + ((b & 15) + 16 * ((n >> 3) & 3)) * 8 + (n & 7);
    xph[off] = h; xph[off + 512] = lo;
  }
  if (idx < 4 * 1024 * 128) {                 // c [(ld)][n][b]
    int ld = idx / (1024 * 128); int l = ld >> 1;
    int rem = idx % (1024 * 128);
    int n = rem >> 7;
    const float* cs = (ld & 1) ? c0r : c0;
    call[idx] = cs[l * 1024 + n];
  }
  if (idx < 4 * 4096) {                       // bias[(l*2+dir)][m]
    int ld = idx / 4096; int l = ld >> 1, dir = ld & 1;
    int m = idx & 4095;
    bias[idx] = (dir ? b_ihr : b_ih)[l * 4096 + m] + (dir ? b_hhr : b_hh)[l * 4096 + m];
  }
  if (idx < 128 * 1024) {                     // XPX: x0 = emb[yy[:,0]]
    int b = idx >> 10, k = idx & 1023;
    int e = yy[b * NT];
    float v = emb[(size_t)e * 1024 + k];
    unsigned short h, lo; split_bf(v, h, lo);
    size_t off = ((size_t)(k >> 5) * 8 + (b >> 4)) * 1024
               + ((b & 15) + 16 * ((k >> 3) & 3)) * 8 + (k & 7);
    xpx[off] = h; xpx[off + 512] = lo;
  }
  if (idx < NB) ended[idx] = 0;
}

// ---------------- one-time weight pre-split (16-row gate-interleaved mtiles) --
__global__ void k_packW(const float* W_ih, const float* W_hh,
                        const float* W_ihr, const float* W_hhr,
                        unsigned short* WP)
{
  int idx = blockIdx.x * 256 + threadIdx.x;   // 16384 blocks -> 4,194,304
  int l = idx & 63;
  int frag = idx >> 6;                        // ((ld*256+mq)*64+ktile)
  int ktile = frag & 63;
  int mq = (frag >> 6) & 255;
  int ld = frag >> 14;
  int layer = ld >> 1, dir = ld & 1;
  int s = l & 15;
  int gate = s >> 2;
  int m = gate * 1024 + mq * 4 + (s & 3);
  int kg = ktile * 32 + (l >> 4) * 8;
  const float* base;
  if (kg < 1024) base = (dir ? W_ihr : W_ih) + ((size_t)layer * 4096 + m) * 1024 + kg;
  else           base = (dir ? W_hhr : W_hh) + ((size_t)layer * 4096 + m) * 1024 + (kg - 1024);
  float4 a0 = *(const float4*)base, a1 = *(const float4*)(base + 4);
  s8v hi, lo; cvt8(a0, a1, hi, lo);
  unsigned short* outp = WP + (size_t)frag * 1024 + l * 8;
  *(s8v*)outp = hi;
  *(s8v*)(outp + 512) = lo;
}

// ---------------- reduction helpers (acc[8] variant) -------------------------
__device__ __forceinline__ void red_write8(float* red, int slot, int l, const f4v (&acc)[8])
{
  #pragma unroll
  for (int bt = 0; bt < 8; bt++)
    *(f4v*)&red[(size_t)slot * 2048 + bt * 256 + l * 4] = acc[bt];
}
__device__ __forceinline__ void red_add8(const float* red, int slot, int l, f4v (&acc)[8])
{
  #pragma unroll
  for (int bt = 0; bt < 8; bt++)
    acc[bt] += *(const f4v*)&red[(size_t)slot * 2048 + bt * 256 + l * 4];
}
__device__ __forceinline__ void gloadB(const unsigned short* Bb, int kk,
                                       s8v (&h)[8], s8v (&lo)[8])
{
  #pragma unroll
  for (int bt = 0; bt < 8; bt++) {
    const unsigned short* q = Bb + ((size_t)(kk * 8 + bt) << 10);
    h[bt] = *(const s8v*)q; lo[bt] = *(const s8v*)(q + 512);
  }
}

struct CellP {
  const unsigned short* WP;
  const float* Wih; const float* Whh; const float* Wihr; const float* Whhr;
  const float* bias; float* c; const unsigned short* xpx; float* Ht;
};

// ---------------- fused cell GEMM + gates, one kernel per layer --------------
// grid (256 mq, 2 dir) = 512 blocks (2/CU), 512 thr; block = 16 m-rows
// (4 n x 4 gates) x 128 b x K=2048; wave w = K-chunk w*256.
template<int LAYER, int PACKED>
__global__ __launch_bounds__(512, 4) void k_cell(CellP p, const unsigned short* xpR,
                                                 unsigned short* xpW)
{
  __shared__ __align__(16) float lds[10240];           // 40 KB: 4 red slots + zs
  const int mq = blockIdx.x, dir = blockIdx.y, tid = threadIdx.x;
  const int l = tid & 63, w = tid >> 6;                // w = K-chunk 0..7
  const int lr = l & 15, lk = l >> 4;

  const unsigned short* Bb;
  if (LAYER == 0)
    Bb = (w < 4) ? p.xpx + (size_t)w * 65536
                 : xpR + (size_t)(dir * 64 + (w - 4) * 8) * 8192;
  else
    Bb = (w < 4) ? xpW + (size_t)(dir * 64 + w * 8) * 8192
                 : xpR + (size_t)(dir * 64 + 32 + (w - 4) * 8) * 8192;
  Bb += l * 8;

  f4v acc[8];
  #pragma unroll
  for (int bt = 0; bt < 8; bt++) acc[bt] = (f4v)(0.0f);

  if (PACKED) {
    const unsigned short* Wb = p.WP + (size_t)(LAYER * 2 + dir) * 16777216ULL
        + (((size_t)mq * 64 + (size_t)w * 8) << 10) + l * 8;
    s8v whc = *(const s8v*)Wb, wlc = *(const s8v*)(Wb + 512);
    #pragma unroll 1
    for (int kk = 0; kk < 8; kk++) {
      s8v bh[8], bl[8];
      gloadB(Bb, kk, bh, bl);
      s8v whn, wln;
      if (kk < 7) {                                    // W depth-1 prefetch
        const unsigned short* q = Wb + ((size_t)(kk + 1) << 10);
        whn = *(const s8v*)q; wln = *(const s8v*)(q + 512);
      }
      #pragma unroll
      for (int bt = 0; bt < 8; bt++) {
        acc[bt] = __builtin_amdgcn_mfma_f32_16x16x32_bf16(whc, bh[bt], acc[bt], 0, 0, 0);
        acc[bt] = __builtin_amdgcn_mfma_f32_16x16x32_bf16(whc, bl[bt], acc[bt], 0, 0, 0);
        acc[bt] = __builtin_amdgcn_mfma_f32_16x16x32_bf16(wlc, bh[bt], acc[bt], 0, 0, 0);
      }
      if (kk < 7) { whc = whn; wlc = wln; }
    }
  } else {
    const float* Wsel = ((w < 4) ? (dir ? p.Wihr : p.Wih) : (dir ? p.Whhr : p.Whh))
                      + (size_t)LAYER * 4194304;
    int col0 = (w & 3) * 256 + lk * 8;
    int m = (lr >> 2) * 1024 + mq * 4 + (lr & 3);
    const float* Wr = Wsel + (size_t)m * 1024 + col0;
    float4 ac0 = *(const float4*)Wr, ac1 = *(const float4*)(Wr + 4);
    #pragma unroll 1
    for (int kk = 0; kk < 8; kk++) {
      s8v bh[8], bl[8];
      gloadB(Bb, kk, bh, bl);
      float4 an0, an1;
      if (kk < 7) {
        an0 = *(const float4*)(Wr + (kk + 1) * 32);
        an1 = *(const float4*)(Wr + (kk + 1) * 32 + 4);
      }
      s8v wh, wl;
      cvt8(ac0, ac1, wh, wl);
      #pragma unroll
      for (int bt = 0; bt < 8; bt++) {
        acc[bt] = __builtin_amdgcn_mfma_f32_16x16x32_bf16(wh, bh[bt], acc[bt], 0, 0, 0);
        acc[bt] = __builtin_amdgcn_mfma_f32_16x16x32_bf16(wh, bl[bt], acc[bt], 0, 0, 0);
        acc[bt] = __builtin_amdgcn_mfma_f32_16x16x32_bf16(wl, bh[bt], acc[bt], 0, 0, 0);
      }
      if (kk < 7) { ac0 = an0; ac1 = an1; }
    }
  }

  // ---- in-block K reduction: 8 -> 4 -> 2 -> zs ----
  if (w >= 4) red_write8(lds, w - 4, l, acc);
  __syncthreads();
  if (w < 4) red_add8(lds, w, l, acc);
  __syncthreads();
  if (w == 2 || w == 3) red_write8(lds, w - 2, l, acc);
  __syncthreads();
  if (w < 2) red_add8(lds, w, l, acc);
  __syncthreads();
  if (w < 2) red_write8(lds, w, l, acc);
  __syncthreads();
  float* zs = lds + 8192;                     // [16 slot][128 b]
  {
    f4v s = *(const f4v*)&lds[(size_t)tid * 4];
    s += *(const f4v*)&lds[2048 + (size_t)tid * 4];
    int bt = tid >> 6, ll = tid & 63;
    #pragma unroll
    for (int r = 0; r < 4; r++)
      zs[((ll >> 4) * 4 + r) * 128 + bt * 16 + (ll & 15)] = s[r];
  }
  __syncthreads();

  // ---- fused gates: 512 threads = 4 n x 128 b, one cell each ----
  // slots: 0-3 = i (nl 0-3), 4-7 = f, 8-11 = g, 12-15 = o
  {
    int ldg = LAYER * 2 + dir;
    int b = tid & 127, nl = tid >> 7;
    int n = mq * 4 + nl;
    float iv = zs[nl * 128 + b]        + p.bias[ldg * 4096 + n];
    float fv = zs[(4 + nl) * 128 + b]  + p.bias[ldg * 4096 + 1024 + n];
    float gv = zs[(8 + nl) * 128 + b]  + p.bias[ldg * 4096 + 2048 + n];
    float ov = zs[(12 + nl) * 128 + b] + p.bias[ldg * 4096 + 3072 + n];
    float* cp = p.c + ((size_t)ldg * 1024 + n) * 128 + b;
    float cold = *cp;
    float cn = sigmoid_stable(fv) * cold + sigmoid_stable(iv) * tanhf(gv);
    float hn = sigmoid_stable(ov) * tanhf(cn);
    *cp = cn;
    unsigned short hh, lo; split_bf(hn, hh, lo);
    int kt = LAYER * 32 + (n >> 5), n5 = n & 31;
    size_t off = ((size_t)(dir * 64 + kt) * 8 + (b >> 4)) * 1024
               + ((size_t)((b & 15) + 16 * ((n5 >> 3) & 3))) * 8 + (n5 & 7);
    xpW[off] = hh;
    xpW[off + 512] = lo;
    if (LAYER == 1)
      p.Ht[(size_t)dir * 131072 + (size_t)n * 128 + b] = hn;
  }
}

// ---------------- FC GEMM (fp32, verified): fcz[kp][b][e], kp=16 -------------
__global__ __launch_bounds__(256) void k_fc(const float* Ht, const float* fc_W, float* fcz)
{
  int et = blockIdx.x, kp = blockIdx.y;
  int e0 = et * 64;
  int k00 = kp * 128;
  __shared__ __align__(16) float in_s[128][36];
  __shared__ __align__(16) float w_s[64][36];
  int t = threadIdx.x, e_sub = t & 7, bg = t >> 3, b0 = bg * 4;
  float acc[8][4] = {};
  for (int kc = 0; kc < 128; kc += 32) {
    #pragma unroll
    for (int i = 0; i < 4; i++) {
      int flat = t + 256 * i, r = flat >> 3, f4i = flat & 7;
      float4 v = *(const float4*)(Ht + (size_t)r * 2048 + k00 + kc + f4i * 4);
      int sw = (f4i ^ (r >> 2)) & 7;
      *(float4*)&in_s[r][sw * 4] = v;
    }
    #pragma unroll
    for (int i = 0; i < 2; i++) {
      int flat = t + 256 * i, r = flat >> 3, f4i = flat & 7;
      *(float4*)&w_s[r][f4i * 4] =
          *(const float4*)(fc_W + (size_t)(e0 + r) * 2048 + k00 + kc + f4i * 4);
    }
    __syncthreads();
    #pragma unroll
    for (int kq = 0; kq < 8; kq++) {
      int ksw = (kq ^ bg) & 7;
      float4 a4[4];
      #pragma unroll
      for (int ib = 0; ib < 4; ib++) a4[ib] = *(const float4*)&in_s[b0 + ib][ksw * 4];
      float4 w4[8];
      #pragma unroll
      for (int je = 0; je < 8; je++) w4[je] = *(const float4*)&w_s[e_sub + 8 * je][kq * 4];
      #pragma unroll
      for (int je = 0; je < 8; je++)
        #pragma unroll
        for (int ib = 0; ib < 4; ib++)
          acc[je][ib] += a4[ib].x * w4[je].x + a4[ib].y * w4[je].y +
                         a4[ib].z * w4[je].z + a4[ib].w * w4[je].w;
    }
    __syncthreads();
  }
  for (int je = 0; je < 8; je++) {
    int e = e0 + e_sub + 8 * je;
    for (int ib = 0; ib < 4; ib++)
      fcz[((size_t)kp * NB + b0 + ib) * NE + e] = acc[je][ib];
  }
}

// ---------------- finalize: logits, override, argmax, pack next x, softmax ---
__global__ void k_final(const float* fcz, const float* fc_b, int* ended,
                        float* out, int tstep, const float* emb, unsigned short* xpx)
{
  int b = blockIdx.x;
  int t = threadIdx.x;
  __shared__ float sval[256];
  __shared__ int   sidx[256];
  __shared__ float ssum[256];
  bool end = (ended[b] != 0);
  float v[4];
  int e_base = t * 4;
  float4 vv = *(const float4*)&fc_b[e_base];
  #pragma unroll
  for (int p = 0; p < 16; p++)
    add4(vv, *(const float4*)&fcz[((size_t)p * NB + b) * NE + e_base]);
  v[0] = vv.x; v[1] = vv.y; v[2] = vv.z; v[3] = vv.w;
  if (end) {
    #pragma unroll
    for (int j = 0; j < 4; j++) v[j] = (e_base + j == EOSL) ? 1.f : 0.f;
  }
  float bv = v[0]; int bi = e_base;
  #pragma unroll
  for (int j = 1; j < 4; j++) if (v[j] > bv) { bv = v[j]; bi = e_base + j; }
  sval[t] = bv; sidx[t] = bi;
  __syncthreads();
  for (int s = 128; s > 0; s >>= 1) {
    if (t < s) {
      float ov = sval[t + s]; int oi = sidx[t + s];
      if (ov > sval[t] || (ov == sval[t] && oi < sidx[t])) { sval[t] = ov; sidx[t] = oi; }
    }
    __syncthreads();
  }
  float m = sval[0]; int label = sidx[0];
  {
    int k0 = t * 4;
    float4 e4 = *(const float4*)(emb + (size_t)label * 1024 + k0);
    size_t off = ((size_t)(k0 >> 5) * 8 + (b >> 4)) * 1024
               + ((b & 15) + 16 * ((k0 >> 3) & 3)) * 8 + (k0 & 7);
    ushort4 h4, l4;
    unsigned short hh, ll;
    split_bf(e4.x, hh, ll); h4.x = hh; l4.x = ll;
    split_bf(e4.y, hh, ll); h4.y = hh; l4.y = ll;
    split_bf(e4.z, hh, ll); h4.z = hh; l4.z = ll;
    split_bf(e4.w, hh, ll); h4.w = hh; l4.w = ll;
    *(ushort4*)(xpx + off) = h4;
    *(ushort4*)(xpx + off + 512) = l4;
  }
  float ls = 0.f;
  #pragma unroll
  for (int j = 0; j < 4; j++) { v[j] = expf(v[j] - m); ls += v[j]; }
  ssum[t] = ls;
  __syncthreads();
  for (int s = 128; s > 0; s >>= 1) { if (t < s) ssum[t] += ssum[t + s]; __syncthreads(); }
  float inv = 1.f / ssum[0];
  float* orow = out + ((size_t)b * NT + tstep) * NE + e_base;
  #pragma unroll
  for (int j = 0; j < 4; j++) orow[j] = v[j] * inv;
  if (t == 0) ended[b] = (end || label == EOSL) ? 1 : 0;
}

extern "C" void kernel_launch(void* const* d_in, const int* in_sizes, int n_in,
                              void* d_out, int out_size, void* d_ws, size_t ws_size,
                              hipStream_t stream)
{
  const int*   yy    = (const int*)d_in[0];
  const float* h_t   = (const float*)d_in[1];
  const float* h_tr  = (const float*)d_in[2];
  const float* emb   = (const float*)d_in[4];
  const float* W_ih  = (const float*)d_in[5];
  const float* W_hh  = (const float*)d_in[6];
  const float* b_ih  = (const float*)d_in[7];
  const float* b_hh  = (const float*)d_in[8];
  const float* W_ihr = (const float*)d_in[9];
  const float* W_hhr = (const float*)d_in[10];
  const float* b_ihr = (const float*)d_in[11];
  const float* b_hhr = (const float*)d_in[12];
  const float* c0    = (const float*)d_in[13];
  const float* c0r   = (const float*)d_in[14];
  const float* fc_W  = (const float*)d_in[15];
  const float* fc_b  = (const float*)d_in[16];
  float* out = (float*)d_out;

  float* ws = (float*)d_ws;
  float* call = ws + C_OFF;
  float* Ht   = ws + HT_OFF;
  float* fcz  = ws + FCZ_OFF;
  float* bias = ws + BIAS_OFF;
  int* ended  = (int*)(ws + END_OFF);
  unsigned short* xph = (unsigned short*)(ws + XPH_OFF);
  unsigned short* xpx = (unsigned short*)(ws + XPX_OFF);
  unsigned short* WP  = (unsigned short*)(ws + WP_OFF);
  bool packed = ws_size >= TOTAL_PACK_F * sizeof(float);

  k_init<<<2048, 256, 0, stream>>>(yy, h_t, h_tr, c0, c0r, b_ih, b_hh, b_ihr, b_hhr,
                                   emb, xph, xpx, call, bias, ended);
  if (packed)
    k_packW<<<16384, 256, 0, stream>>>(W_ih, W_hh, W_ihr, W_hhr, WP);

  CellP cp;
  cp.WP = WP;
  cp.Wih = W_ih; cp.Whh = W_hh; cp.Wihr = W_ihr; cp.Whhr = W_hhr;
  cp.bias = bias; cp.c = call; cp.xpx = xpx; cp.Ht = Ht;

  for (int t = 0; t < NT; t++) {
    const unsigned short* xpR = xph + (size_t)(t & 1) * 1048576;
    unsigned short* xpW = xph + (size_t)((t & 1) ^ 1) * 1048576;
    if (packed) {
      k_cell<0, 1><<<dim3(256, 2), 512, 0, stream>>>(cp, xpR, xpW);
      k_cell<1, 1><<<dim3(256, 2), 512, 0, stream>>>(cp, xpR, xpW);
    } else {
      k_cell<0, 0><<<dim3(256, 2), 512, 0, stream>>>(cp, xpR, xpW);
      k_cell<1, 0><<<dim3(256, 2), 512, 0, stream>>>(cp, xpR, xpW);
    }
    k_fc<<<dim3(16, 16), 256, 0, stream>>>(Ht, fc_W, fcz);
    k_final<<<128, 256, 0, stream>>>(fcz, fc_b, ended, out, t, emb, xpx);
  }
}

// Round 13
// 19263.515 us; speedup vs baseline: 4.6530x; 1.1030x over previous
//
#include <hip/hip_runtime.h>
#include <math.h>

// B=128, T=256, H=E=1024, L=2, EOS=1
#define NB 128
#define NT 256
#define NH 1024
#define NE 1024
#define G4 4096
#define EOSL 1

// ---------------- workspace layout (float units) ----------------
#define C_OFF    ((size_t)0)          // c [(l*2+dir)][n 1024][b 128] = 524,288
#define FCL_OFF  ((size_t)524288)     // fcl [128 bo][1024 e] = 131,072
#define XFC_OFF  ((size_t)655360)     // packed fc acts: 512 frags x 1024 sh = 262,144 f
#define BIAS_OFF ((size_t)917504)     // 16,384
#define END_OFF  ((size_t)933888)     // 128
#define XPH_OFF  ((size_t)934016)     // 2 parity x 524,288 f
#define XPX_OFF  ((size_t)1982592)    // 131,072 f
#define FCWP_OFF ((size_t)2113664)    // packed fc_W: 4096 frags x 1024 sh = 2,097,152 f
#define WP_OFF   ((size_t)4210816)    // 33,554,432 f
#define TOTAL_MIN_F  ((size_t)4210816)
#define TOTAL_PACK_F ((size_t)37765248)   // ~151.1 MB

typedef __attribute__((ext_vector_type(8))) short s8v;   // 8 bf16 for MFMA A/B
typedef __attribute__((ext_vector_type(4))) float f4v;   // MFMA C/D

__device__ __forceinline__ float sigmoid_stable(float x) {
  if (x >= 0.f) return 1.f / (1.f + expf(-x));
  float ex = expf(x);
  return ex / (1.f + ex);
}
__device__ __forceinline__ unsigned short bf_rne(float x) {
  unsigned u = __float_as_uint(x);
  return (unsigned short)((u + 0x7FFFu + ((u >> 16) & 1u)) >> 16);
}
__device__ __forceinline__ void split_bf(float x, unsigned short& h, unsigned short& l) {
  unsigned u = __float_as_uint(x);
  unsigned hb = (u + 0x7FFFu + ((u >> 16) & 1u)) >> 16;
  h = (unsigned short)hb;
  float r = x - __uint_as_float(hb << 16);   // exact
  l = bf_rne(r);
}
__device__ __forceinline__ void cvt8(float4 a0, float4 a1, s8v& hi, s8v& lo)
{
  const float v[8] = {a0.x, a0.y, a0.z, a0.w, a1.x, a1.y, a1.z, a1.w};
  #pragma unroll
  for (int j = 0; j < 8; j++) {
    unsigned short h, l; split_bf(v[j], h, l);
    hi[j] = (short)h; lo[j] = (short)l;
  }
}

// frag layouts (verified rounds 0-12):
//  B (acts): lane l holds B[k=(l>>4)*8+r][col=l&15]; frag = 512 hi + 512 lo shorts;
//    buffer = [ktile][coltile]: frag = (k>>5)*8 + (col>>4), lane = (col&15)+16*((k>>3)&3), reg = k&7.
//  A (wgts): lane l holds A[slot=l&15][k=(l>>4)*8+r].
//  cell WP 16-row mtiles: mq in [0,256): slot s -> m = (s>>2)*1024 + mq*4 + (s&3).
//  fc  WP plain mtiles:   mq in [0,64):  slot s -> m = mq*16 + s.
//  C/D: col=lane&15, row slot=(lane>>4)*4+reg.
// Reference FC input wh = concat(h,hr).T.reshape(B,-1) is a SHUFFLE:
//  wh[bo,k] = Hc[k%128][bo*16 + k//128]; hn(dir,n,b) lands at bo = dir*64 + n/16,
//  k = (n%16)*128 + b. k_cell<1> scatters hn into xfc frags with that mapping;
//  k_fcm is then a plain M=1024 K=2048 N=128(bo) MFMA GEMM. (R10's bug: ignored shuffle.)

// ---------------- init ----------------
__global__ void k_init(const int* yy, const float* h_t, const float* h_tr,
                       const float* c0, const float* c0r,
                       const float* b_ih, const float* b_hh,
                       const float* b_ihr, const float* b_hhr,
                       const float* emb,
                       unsigned short* xph, unsigned short* xpx,
                       float* call, float* bias, int* ended)
{
  int idx = blockIdx.x * 256 + threadIdx.x;   // 2048 blocks -> 524288
  if (idx < 2 * 2048 * 128) {                 // XPH parity-0
    int dir = idx / (2048 * 128); int rem = idx % (2048 * 128);
    int row = rem >> 7, b = rem & 127;
    int l = row >> 10, n = row & 1023;
    const float* src = dir ? h_tr : h_t;
    float v = src[((size_t)l * 128 + b) * 1024 + n];
    unsigned short h, lo; split_bf(v, h, lo);
    size_t off = ((size_t)(dir * 64 + (row >> 5)) * 8 + (b >> 4)) * 1024
               + ((b & 15) + 16 * ((n >> 3) & 3)) * 8 + (n & 7);
    xph[off] = h; xph[off + 512] = lo;
  }
  if (idx < 4 * 1024 * 128) {                 // c [(ld)][n][b]
    int ld = idx / (1024 * 128); int l = ld >> 1;
    int rem = idx % (1024 * 128);
    int n = rem >> 7;
    const float* cs = (ld & 1) ? c0r : c0;
    call[idx] = cs[l * 1024 + n];
  }
  if (idx < 4 * 4096) {                       // bias[(l*2+dir)][m]
    int ld = idx / 4096; int l = ld >> 1, dir = ld & 1;
    int m = idx & 4095;
    bias[idx] = (dir ? b_ihr : b_ih)[l * 4096 + m] + (dir ? b_hhr : b_hh)[l * 4096 + m];
  }
  if (idx < 128 * 1024) {                     // XPX: x0 = emb[yy[:,0]]
    int b = idx >> 10, k = idx & 1023;
    int e = yy[b * NT];
    float v = emb[(size_t)e * 1024 + k];
    unsigned short h, lo; split_bf(v, h, lo);
    size_t off = ((size_t)(k >> 5) * 8 + (b >> 4)) * 1024
               + ((b & 15) + 16 * ((k >> 3) & 3)) * 8 + (k & 7);
    xpx[off] = h; xpx[off + 512] = lo;
  }
  if (idx < NB) ended[idx] = 0;
}

// ---------------- one-time weight pre-split (cell 16-row mtiles + fc) --------
__global__ void k_packW(const float* W_ih, const float* W_hh,
                        const float* W_ihr, const float* W_hhr,
                        const float* fc_W,
                        unsigned short* WP, unsigned short* fcWP)
{
  int idx = blockIdx.x * 256 + threadIdx.x;   // 17408 blocks -> 4,456,448
  if (idx < 4194304) {
    int l = idx & 63;
    int frag = idx >> 6;                      // ((ld*256+mq)*64+ktile)
    int ktile = frag & 63;
    int mq = (frag >> 6) & 255;
    int ld = frag >> 14;
    int layer = ld >> 1, dir = ld & 1;
    int s = l & 15;
    int gate = s >> 2;
    int m = gate * 1024 + mq * 4 + (s & 3);
    int kg = ktile * 32 + (l >> 4) * 8;
    const float* base;
    if (kg < 1024) base = (dir ? W_ihr : W_ih) + ((size_t)layer * 4096 + m) * 1024 + kg;
    else           base = (dir ? W_hhr : W_hh) + ((size_t)layer * 4096 + m) * 1024 + (kg - 1024);
    float4 a0 = *(const float4*)base, a1 = *(const float4*)(base + 4);
    s8v hi, lo; cvt8(a0, a1, hi, lo);
    unsigned short* outp = WP + (size_t)frag * 1024 + l * 8;
    *(s8v*)outp = hi;
    *(s8v*)(outp + 512) = lo;
  } else if (idx < 4456448) {                 // fc weights: frag = mq*64 + ktile
    int i2 = idx - 4194304;
    int l = i2 & 63;
    int frag = i2 >> 6;                       // [0,4096)
    int ktile = frag & 63, mq = frag >> 6;    // mq [0,64)
    int m = mq * 16 + (l & 15);
    int kg = ktile * 32 + (l >> 4) * 8;
    const float* base = fc_W + (size_t)m * 2048 + kg;
    float4 a0 = *(const float4*)base, a1 = *(const float4*)(base + 4);
    s8v hi, lo; cvt8(a0, a1, hi, lo);
    unsigned short* outp = fcWP + (size_t)frag * 1024 + l * 8;
    *(s8v*)outp = hi;
    *(s8v*)(outp + 512) = lo;
  }
}

// ---------------- reduction helpers (acc[8]) ---------------------------------
__device__ __forceinline__ void red_write8(float* red, int slot, int l, const f4v (&acc)[8])
{
  #pragma unroll
  for (int bt = 0; bt < 8; bt++)
    *(f4v*)&red[(size_t)slot * 2048 + bt * 256 + l * 4] = acc[bt];
}
__device__ __forceinline__ void red_add8(const float* red, int slot, int l, f4v (&acc)[8])
{
  #pragma unroll
  for (int bt = 0; bt < 8; bt++)
    acc[bt] += *(const f4v*)&red[(size_t)slot * 2048 + bt * 256 + l * 4];
}
__device__ __forceinline__ void gloadB(const unsigned short* Bb, int kk,
                                       s8v (&h)[8], s8v (&lo)[8])
{
  #pragma unroll
  for (int bt = 0; bt < 8; bt++) {
    const unsigned short* q = Bb + ((size_t)(kk * 8 + bt) << 10);
    h[bt] = *(const s8v*)q; lo[bt] = *(const s8v*)(q + 512);
  }
}
// shared reduce: 8 wave partials -> zs = lds+8192 ([16 slot][128 col])
__device__ __forceinline__ void reduce8_to_zs(float* lds, int tid, int l, int w,
                                              f4v (&acc)[8])
{
  if (w >= 4) red_write8(lds, w - 4, l, acc);
  __syncthreads();
  if (w < 4) red_add8(lds, w, l, acc);
  __syncthreads();
  if (w == 2 || w == 3) red_write8(lds, w - 2, l, acc);
  __syncthreads();
  if (w < 2) red_add8(lds, w, l, acc);
  __syncthreads();
  if (w < 2) red_write8(lds, w, l, acc);
  __syncthreads();
  float* zs = lds + 8192;
  {
    f4v s = *(const f4v*)&lds[(size_t)tid * 4];
    s += *(const f4v*)&lds[2048 + (size_t)tid * 4];
    int bt = tid >> 6, ll = tid & 63;
    #pragma unroll
    for (int r = 0; r < 4; r++)
      zs[((ll >> 4) * 4 + r) * 128 + bt * 16 + (ll & 15)] = s[r];
  }
  __syncthreads();
}

struct CellP {
  const unsigned short* WP;
  const float* Wih; const float* Whh; const float* Wihr; const float* Whhr;
  const float* bias; float* c; const unsigned short* xpx; unsigned short* xfc;
};

// ---------------- fused cell GEMM + gates, one kernel per layer --------------
// grid (256 mq, 2 dir) = 512 blocks (2/CU), 512 thr; block = 16 m-rows
// (4 n x 4 gates) x 128 b x K=2048; wave w = K-chunk w*256.
template<int LAYER, int PACKED>
__global__ __launch_bounds__(512, 4) void k_cell(CellP p, const unsigned short* xpR,
                                                 unsigned short* xpW)
{
  __shared__ __align__(16) float lds[10240];           // 40 KB
  const int mq = blockIdx.x, dir = blockIdx.y, tid = threadIdx.x;
  const int l = tid & 63, w = tid >> 6;                // w = K-chunk 0..7
  const int lr = l & 15, lk = l >> 4;

  const unsigned short* Bb;
  if (LAYER == 0)
    Bb = (w < 4) ? p.xpx + (size_t)w * 65536
                 : xpR + (size_t)(dir * 64 + (w - 4) * 8) * 8192;
  else
    Bb = (w < 4) ? xpW + (size_t)(dir * 64 + w * 8) * 8192
                 : xpR + (size_t)(dir * 64 + 32 + (w - 4) * 8) * 8192;
  Bb += l * 8;

  f4v acc[8];
  #pragma unroll
  for (int bt = 0; bt < 8; bt++) acc[bt] = (f4v)(0.0f);

  if (PACKED) {
    const unsigned short* Wb = p.WP + (size_t)(LAYER * 2 + dir) * 16777216ULL
        + (((size_t)mq * 64 + (size_t)w * 8) << 10) + l * 8;
    s8v whc = *(const s8v*)Wb, wlc = *(const s8v*)(Wb + 512);
    #pragma unroll 1
    for (int kk = 0; kk < 8; kk++) {
      s8v bh[8], bl[8];
      gloadB(Bb, kk, bh, bl);
      s8v whn, wln;
      if (kk < 7) {                                    // W depth-1 prefetch
        const unsigned short* q = Wb + ((size_t)(kk + 1) << 10);
        whn = *(const s8v*)q; wln = *(const s8v*)(q + 512);
      }
      #pragma unroll
      for (int bt = 0; bt < 8; bt++) {
        acc[bt] = __builtin_amdgcn_mfma_f32_16x16x32_bf16(whc, bh[bt], acc[bt], 0, 0, 0);
        acc[bt] = __builtin_amdgcn_mfma_f32_16x16x32_bf16(whc, bl[bt], acc[bt], 0, 0, 0);
        acc[bt] = __builtin_amdgcn_mfma_f32_16x16x32_bf16(wlc, bh[bt], acc[bt], 0, 0, 0);
      }
      if (kk < 7) { whc = whn; wlc = wln; }
    }
  } else {
    const float* Wsel = ((w < 4) ? (dir ? p.Wihr : p.Wih) : (dir ? p.Whhr : p.Whh))
                      + (size_t)LAYER * 4194304;
    int col0 = (w & 3) * 256 + lk * 8;
    int m = (lr >> 2) * 1024 + mq * 4 + (lr & 3);
    const float* Wr = Wsel + (size_t)m * 1024 + col0;
    float4 ac0 = *(const float4*)Wr, ac1 = *(const float4*)(Wr + 4);
    #pragma unroll 1
    for (int kk = 0; kk < 8; kk++) {
      s8v bh[8], bl[8];
      gloadB(Bb, kk, bh, bl);
      float4 an0, an1;
      if (kk < 7) {
        an0 = *(const float4*)(Wr + (kk + 1) * 32);
        an1 = *(const float4*)(Wr + (kk + 1) * 32 + 4);
      }
      s8v wh, wl;
      cvt8(ac0, ac1, wh, wl);
      #pragma unroll
      for (int bt = 0; bt < 8; bt++) {
        acc[bt] = __builtin_amdgcn_mfma_f32_16x16x32_bf16(wh, bh[bt], acc[bt], 0, 0, 0);
        acc[bt] = __builtin_amdgcn_mfma_f32_16x16x32_bf16(wh, bl[bt], acc[bt], 0, 0, 0);
        acc[bt] = __builtin_amdgcn_mfma_f32_16x16x32_bf16(wl, bh[bt], acc[bt], 0, 0, 0);
      }
      if (kk < 7) { ac0 = an0; ac1 = an1; }
    }
  }

  reduce8_to_zs(lds, tid, l, w, acc);
  float* zs = lds + 8192;                     // [16 slot][128 b]

  // ---- fused gates: 512 threads = 4 n x 128 b, one cell each ----
  {
    int ldg = LAYER * 2 + dir;
    int b = tid & 127, nl = tid >> 7;
    int n = mq * 4 + nl;
    float iv = zs[nl * 128 + b]        + p.bias[ldg * 4096 + n];
    float fv = zs[(4 + nl) * 128 + b]  + p.bias[ldg * 4096 + 1024 + n];
    float gv = zs[(8 + nl) * 128 + b]  + p.bias[ldg * 4096 + 2048 + n];
    float ov = zs[(12 + nl) * 128 + b] + p.bias[ldg * 4096 + 3072 + n];
    float* cp = p.c + ((size_t)ldg * 1024 + n) * 128 + b;
    float cold = *cp;
    float cn = sigmoid_stable(fv) * cold + sigmoid_stable(iv) * tanhf(gv);
    float hn = sigmoid_stable(ov) * tanhf(cn);
    *cp = cn;
    unsigned short hh, lo; split_bf(hn, hh, lo);
    int kt = LAYER * 32 + (n >> 5), n5 = n & 31;
    size_t off = ((size_t)(dir * 64 + kt) * 8 + (b >> 4)) * 1024
               + ((size_t)((b & 15) + 16 * ((n5 >> 3) & 3))) * 8 + (n5 & 7);
    xpW[off] = hh;
    xpW[off + 512] = lo;
    if (LAYER == 1) {
      // scatter into fc B-frags: bo = dir*64 + n/16, k = (n%16)*128 + b
      int bo = dir * 64 + (n >> 4);
      int k = (n & 15) * 128 + b;
      size_t fo = ((size_t)((k >> 5) * 8 + (bo >> 4))) * 1024
                + ((size_t)((bo & 15) + 16 * ((k >> 3) & 3))) * 8 + (k & 7);
      p.xfc[fo] = hh;
      p.xfc[fo + 512] = lo;
    }
  }
}

// ---------------- FC via MFMA: fcl[bo][e] = wh @ fc_W.T + fc_b ---------------
// grid (64 mq), 512 thr; block = 16 e-rows x 128 bo x K=2048 (in-block K-split-8)
template<int PACKED>
__global__ __launch_bounds__(512, 4) void k_fcm(const unsigned short* fcWP, const float* fcW,
                                                const unsigned short* xfc, const float* fcb,
                                                float* fcl)
{
  __shared__ __align__(16) float lds[10240];
  const int mq = blockIdx.x, tid = threadIdx.x;
  const int l = tid & 63, w = tid >> 6;
  const int lr = l & 15, lk = l >> 4;
  const unsigned short* Bb = xfc + (((size_t)w * 64) << 10) + l * 8;

  f4v acc[8];
  #pragma unroll
  for (int bt = 0; bt < 8; bt++) acc[bt] = (f4v)(0.0f);

  if (PACKED) {
    const unsigned short* Wb = fcWP + (((size_t)mq * 64 + (size_t)w * 8) << 10) + l * 8;
    s8v whc = *(const s8v*)Wb, wlc = *(const s8v*)(Wb + 512);
    #pragma unroll 1
    for (int kk = 0; kk < 8; kk++) {
      s8v bh[8], bl[8];
      gloadB(Bb, kk, bh, bl);
      s8v whn, wln;
      if (kk < 7) {
        const unsigned short* q = Wb + ((size_t)(kk + 1) << 10);
        whn = *(const s8v*)q; wln = *(const s8v*)(q + 512);
      }
      #pragma unroll
      for (int bt = 0; bt < 8; bt++) {
        acc[bt] = __builtin_amdgcn_mfma_f32_16x16x32_bf16(whc, bh[bt], acc[bt], 0, 0, 0);
        acc[bt] = __builtin_amdgcn_mfma_f32_16x16x32_bf16(whc, bl[bt], acc[bt], 0, 0, 0);
        acc[bt] = __builtin_amdgcn_mfma_f32_16x16x32_bf16(wlc, bh[bt], acc[bt], 0, 0, 0);
      }
      if (kk < 7) { whc = whn; wlc = wln; }
    }
  } else {
    int m = mq * 16 + lr;
    const float* Wr = fcW + (size_t)m * 2048 + w * 256 + lk * 8;
    float4 ac0 = *(const float4*)Wr, ac1 = *(const float4*)(Wr + 4);
    #pragma unroll 1
    for (int kk = 0; kk < 8; kk++) {
      s8v bh[8], bl[8];
      gloadB(Bb, kk, bh, bl);
      float4 an0, an1;
      if (kk < 7) {
        an0 = *(const float4*)(Wr + (kk + 1) * 32);
        an1 = *(const float4*)(Wr + (kk + 1) * 32 + 4);
      }
      s8v wh, wl;
      cvt8(ac0, ac1, wh, wl);
      #pragma unroll
      for (int bt = 0; bt < 8; bt++) {
        acc[bt] = __builtin_amdgcn_mfma_f32_16x16x32_bf16(wh, bh[bt], acc[bt], 0, 0, 0);
        acc[bt] = __builtin_amdgcn_mfma_f32_16x16x32_bf16(wh, bl[bt], acc[bt], 0, 0, 0);
        acc[bt] = __builtin_amdgcn_mfma_f32_16x16x32_bf16(wl, bh[bt], acc[bt], 0, 0, 0);
      }
      if (kk < 7) { ac0 = an0; ac1 = an1; }
    }
  }

  reduce8_to_zs(lds, tid, l, w, acc);
  float* zs = lds + 8192;                     // [16 slot][128 bo]

  // epilogue: e = mq*16 + slot; +bias; 16B-contiguous fcl write
  {
    int bo = tid & 127, sg = tid >> 7;
    f4v o;
    #pragma unroll
    for (int r = 0; r < 4; r++)
      o[r] = zs[(sg * 4 + r) * 128 + bo] + fcb[mq * 16 + sg * 4 + r];
    *(f4v*)(fcl + (size_t)bo * 1024 + mq * 16 + sg * 4) = o;
  }
}

// ---------------- finalize: logits, override, argmax, pack next x, softmax ---
__global__ void k_final(const float* fcl, int* ended, float* out, int tstep,
                        const float* emb, unsigned short* xpx)
{
  int b = blockIdx.x;
  int t = threadIdx.x;
  __shared__ float sval[256];
  __shared__ int   sidx[256];
  __shared__ float ssum[256];
  bool end = (ended[b] != 0);
  float v[4];
  int e_base = t * 4;
  float4 vv = *(const float4*)&fcl[(size_t)b * 1024 + e_base];
  v[0] = vv.x; v[1] = vv.y; v[2] = vv.z; v[3] = vv.w;
  if (end) {
    #pragma unroll
    for (int j = 0; j < 4; j++) v[j] = (e_base + j == EOSL) ? 1.f : 0.f;
  }
  float bv = v[0]; int bi = e_base;
  #pragma unroll
  for (int j = 1; j < 4; j++) if (v[j] > bv) { bv = v[j]; bi = e_base + j; }
  sval[t] = bv; sidx[t] = bi;
  __syncthreads();
  for (int s = 128; s > 0; s >>= 1) {
    if (t < s) {
      float ov = sval[t + s]; int oi = sidx[t + s];
      if (ov > sval[t] || (ov == sval[t] && oi < sidx[t])) { sval[t] = ov; sidx[t] = oi; }
    }
    __syncthreads();
  }
  float m = sval[0]; int label = sidx[0];
  {
    int k0 = t * 4;
    float4 e4 = *(const float4*)(emb + (size_t)label * 1024 + k0);
    size_t off = ((size_t)(k0 >> 5) * 8 + (b >> 4)) * 1024
               + ((b & 15) + 16 * ((k0 >> 3) & 3)) * 8 + (k0 & 7);
    ushort4 h4, l4;
    unsigned short hh, ll;
    split_bf(e4.x, hh, ll); h4.x = hh; l4.x = ll;
    split_bf(e4.y, hh, ll); h4.y = hh; l4.y = ll;
    split_bf(e4.z, hh, ll); h4.z = hh; l4.z = ll;
    split_bf(e4.w, hh, ll); h4.w = hh; l4.w = ll;
    *(ushort4*)(xpx + off) = h4;
    *(ushort4*)(xpx + off + 512) = l4;
  }
  float ls = 0.f;
  #pragma unroll
  for (int j = 0; j < 4; j++) { v[j] = expf(v[j] - m); ls += v[j]; }
  ssum[t] = ls;
  __syncthreads();
  for (int s = 128; s > 0; s >>= 1) { if (t < s) ssum[t] += ssum[t + s]; __syncthreads(); }
  float inv = 1.f / ssum[0];
  float* orow = out + ((size_t)b * NT + tstep) * NE + e_base;
  #pragma unroll
  for (int j = 0; j < 4; j++) orow[j] = v[j] * inv;
  if (t == 0) ended[b] = (end || label == EOSL) ? 1 : 0;
}

extern "C" void kernel_launch(void* const* d_in, const int* in_sizes, int n_in,
                              void* d_out, int out_size, void* d_ws, size_t ws_size,
                              hipStream_t stream)
{
  const int*   yy    = (const int*)d_in[0];
  const float* h_t   = (const float*)d_in[1];
  const float* h_tr  = (const float*)d_in[2];
  const float* emb   = (const float*)d_in[4];
  const float* W_ih  = (const float*)d_in[5];
  const float* W_hh  = (const float*)d_in[6];
  const float* b_ih  = (const float*)d_in[7];
  const float* b_hh  = (const float*)d_in[8];
  const float* W_ihr = (const float*)d_in[9];
  const float* W_hhr = (const float*)d_in[10];
  const float* b_ihr = (const float*)d_in[11];
  const float* b_hhr = (const float*)d_in[12];
  const float* c0    = (const float*)d_in[13];
  const float* c0r   = (const float*)d_in[14];
  const float* fc_W  = (const float*)d_in[15];
  const float* fc_b  = (const float*)d_in[16];
  float* out = (float*)d_out;

  float* ws = (float*)d_ws;
  float* call = ws + C_OFF;
  float* fcl  = ws + FCL_OFF;
  float* bias = ws + BIAS_OFF;
  int* ended  = (int*)(ws + END_OFF);
  unsigned short* xfc  = (unsigned short*)(ws + XFC_OFF);
  unsigned short* xph  = (unsigned short*)(ws + XPH_OFF);
  unsigned short* xpx  = (unsigned short*)(ws + XPX_OFF);
  unsigned short* fcWP = (unsigned short*)(ws + FCWP_OFF);
  unsigned short* WP   = (unsigned short*)(ws + WP_OFF);
  bool packed = ws_size >= TOTAL_PACK_F * sizeof(float);

  k_init<<<2048, 256, 0, stream>>>(yy, h_t, h_tr, c0, c0r, b_ih, b_hh, b_ihr, b_hhr,
                                   emb, xph, xpx, call, bias, ended);
  if (packed)
    k_packW<<<17408, 256, 0, stream>>>(W_ih, W_hh, W_ihr, W_hhr, fc_W, WP, fcWP);

  CellP cp;
  cp.WP = WP;
  cp.Wih = W_ih; cp.Whh = W_hh; cp.Wihr = W_ihr; cp.Whhr = W_hhr;
  cp.bias = bias; cp.c = call; cp.xpx = xpx; cp.xfc = xfc;

  for (int t = 0; t < NT; t++) {
    const unsigned short* xpR = xph + (size_t)(t & 1) * 1048576;
    unsigned short* xpW = xph + (size_t)((t & 1) ^ 1) * 1048576;
    if (packed) {
      k_cell<0, 1><<<dim3(256, 2), 512, 0, stream>>>(cp, xpR, xpW);
      k_cell<1, 1><<<dim3(256, 2), 512, 0, stream>>>(cp, xpR, xpW);
      k_fcm<1><<<64, 512, 0, stream>>>(fcWP, fc_W, xfc, fc_b, fcl);
    } else {
      k_cell<0, 0><<<dim3(256, 2), 512, 0, stream>>>(cp, xpR, xpW);
      k_cell<1, 0><<<dim3(256, 2), 512, 0, stream>>>(cp, xpR, xpW);
      k_fcm<0><<<64, 512, 0, stream>>>(fcWP, fc_W, xfc, fc_b, fcl);
    }
    k_final<<<128, 256, 0, stream>>>(fcl, ended, out, t, emb, xpx);
  }
}